// Round 8
// baseline (121.457 us; speedup 1.0000x reference)
//
#include <hip/hip_runtime.h>
#include <math.h>

namespace {
constexpr float LN_EPS = 1e-5f;

typedef unsigned short u16;
typedef __attribute__((ext_vector_type(8))) short bh8;
typedef __attribute__((ext_vector_type(4))) float fv4;

__device__ __forceinline__ float4 ld4(const float* p) { return *reinterpret_cast<const float4*>(p); }

__device__ __forceinline__ float b2f(u16 x) {
  union { float f; unsigned u; } c; c.u = ((unsigned)x) << 16; return c.f;
}
__device__ __forceinline__ u16 f2b(float f) {  // RTN-even
  union { float f; unsigned u; } c; c.f = f;
  unsigned u = c.u;
  u += 0x7FFFu + ((u >> 16) & 1u);
  return (u16)(u >> 16);
}
__device__ __forceinline__ unsigned pk2(float a, float b) {
  return (unsigned)f2b(a) | ((unsigned)f2b(b) << 16);
}
__device__ __forceinline__ uint4 pack8(const float* v) {
  uint4 r; r.x = pk2(v[0], v[1]); r.y = pk2(v[2], v[3]); r.z = pk2(v[4], v[5]); r.w = pk2(v[6], v[7]);
  return r;
}

// XOR-swizzled LDS tile access: [R][64] u16, 16B slots, c8 ^= row&7
__device__ __forceinline__ bh8 lds_rd(const u16* S, int row, int c8) {
  return *(const bh8*)&S[row * 64 + ((c8 ^ (row & 7)) << 3)];
}

struct FA {
  const float *q, *k, *Wq, *Wk, *Wv, *Wfc, *Wg, *bg, *Wvp, *bvp;
  const float *ln1g, *ln1b, *ln2g, *ln2b;
  float* out;
  u16 *WkT_bf, *Wv_bf, *Wfc_bf, *k_bf, *kT_bf, *qh_bf;
  float *gam, *bet, *condpre;
  u16 *cb_bf, *cbT_bf, *u_bf, *w1_bf;
  float *c2, *c3, *c4;
  u16* A96_bf;
  float *sum_be, *sum_be2, *P;
  u16* s_bf;
  u16 *cbsq_bf, *w_bf, *W1_bf;
  float *S1, *S2;
  u16* attn_bf;
  float *K1, *K2;
};

// ===========================================================================
// bf16 GEMM core 64x64 (verified). epi: 0 f32, 1 bf16, 5 u-remap,
// 6 u-remap + fused w1 (e0=gam row-indexed, e1=ln2g, Cb2=w1 out)
// ===========================================================================
struct GA {
  const u16* A; const u16* B; const u16* Balt;
  long lda, ldb, sAz, sBz;
  float* Cf; u16* Cb; u16* Cb2;
  long ldc, sCz;
  int M, K, epi;
  const float* e0; const float* e1;
};

__device__ __forceinline__ void gemm_core(const GA& a, u16* As, u16* Bs,
                                          int bx, int by, int bz, int t) {
  const int z = bz;
  const int bm0 = bx * 64, bn0 = by * 64;
  const int lane = t & 63, w = t >> 6;
  const int wm = (w >> 1) * 32, wn = (w & 1) * 32;
  const u16* Ab = a.A + (long)z * a.sAz;
  const u16* Bbase = (a.Balt != nullptr && bm0 >= 64) ? a.Balt : a.B;
  const u16* Bb = Bbase + (long)z * a.sBz;

  const int sr = t >> 3, sc8 = t & 7, sc = sc8 * 8;
  int ar0 = bm0 + sr;      if (ar0 > a.M - 1) ar0 = a.M - 1;
  int ar1 = bm0 + sr + 32; if (ar1 > a.M - 1) ar1 = a.M - 1;
  const u16* ap0 = Ab + (long)ar0 * a.lda + sc;
  const u16* ap1 = Ab + (long)ar1 * a.lda + sc;
  const u16* bp0 = Bb + (long)(bn0 + sr) * a.ldb + sc;
  const u16* bp1 = Bb + (long)(bn0 + sr + 32) * a.ldb + sc;
  const int iA0 = sr * 64 + ((sc8 ^ (sr & 7)) << 3);
  const int iA1 = iA0 + 32 * 64;

  fv4 zero = {0.f, 0.f, 0.f, 0.f};
  fv4 acc00 = zero, acc01 = zero, acc10 = zero, acc11 = zero;
  const int r0 = lane & 15, kq8 = lane >> 4;
  const int nk = a.K >> 6;

  uint4 av0 = *(const uint4*)ap0, av1 = *(const uint4*)ap1;
  uint4 bv0 = *(const uint4*)bp0, bv1 = *(const uint4*)bp1;
  for (int kt = 0; kt < nk; ++kt) {
    __syncthreads();
    *(uint4*)&As[iA0] = av0; *(uint4*)&As[iA1] = av1;
    *(uint4*)&Bs[iA0] = bv0; *(uint4*)&Bs[iA1] = bv1;
    __syncthreads();
    if (kt + 1 < nk) {
      ap0 += 64; ap1 += 64; bp0 += 64; bp1 += 64;
      av0 = *(const uint4*)ap0; av1 = *(const uint4*)ap1;
      bv0 = *(const uint4*)bp0; bv1 = *(const uint4*)bp1;
    }
#pragma unroll
    for (int kc = 0; kc < 2; ++kc) {
      const int c8 = kq8 + 4 * kc;
      bh8 aa0 = lds_rd(As, wm + r0, c8);
      bh8 aa1 = lds_rd(As, wm + 16 + r0, c8);
      bh8 bb0 = lds_rd(Bs, wn + r0, c8);
      bh8 bb1 = lds_rd(Bs, wn + 16 + r0, c8);
      acc00 = __builtin_amdgcn_mfma_f32_16x16x32_bf16(aa0, bb0, acc00, 0, 0, 0);
      acc01 = __builtin_amdgcn_mfma_f32_16x16x32_bf16(aa0, bb1, acc01, 0, 0, 0);
      acc10 = __builtin_amdgcn_mfma_f32_16x16x32_bf16(aa1, bb0, acc10, 0, 0, 0);
      acc11 = __builtin_amdgcn_mfma_f32_16x16x32_bf16(aa1, bb1, acc11, 0, 0, 0);
    }
  }

  fv4 accs[2][2] = {{acc00, acc01}, {acc10, acc11}};
#pragma unroll
  for (int rb = 0; rb < 2; ++rb) {
#pragma unroll
    for (int cbl = 0; cbl < 2; ++cbl) {
#pragma unroll
      for (int j = 0; j < 4; ++j) {
        const int r = bm0 + wm + rb * 16 + (lane >> 4) * 4 + j;
        const int c = bn0 + wn + cbl * 16 + (lane & 15);
        if (r >= a.M) continue;
        const float v = accs[rb][cbl][j];
        if (a.epi == 0) {
          a.Cf[(long)z * a.sCz + (long)r * a.ldc + c] = v;
        } else if (a.epi == 1) {
          a.Cb[(long)z * a.sCz + (long)r * a.ldc + c] = f2b(v);
        } else if (a.epi == 5) {
          a.Cb[((long)r * 8 + z) * a.ldc + c] = f2b(v * 0.125f);
        } else {  // 6: u remap + fused w1
          const u16 ub = f2b(v * 0.125f);
          const long orow = (long)r * 8 + z;
          a.Cb[orow * 512 + c] = ub;
          const float uu = b2f(ub);
          const float t1 = a.e1[c] * uu;
          a.Cb2[orow * 512 + c] = f2b(a.e0[(long)r * 512 + c] * t1);
        }
      }
    }
  }
}

// ===========================================================================
// f32-staging GEMM core 64x64 (verified round 7). epi: 1 bf16, 2 film, 4 +bias
// ===========================================================================
struct GAF {
  const float* Af; const float* Bf;
  long lda, ldb;
  float* Cf; u16* Cb; float* Cf2;
  long ldc;
  int M, K, epi;
  const float* e0;
};

__device__ __forceinline__ void gemm_core_f32(const GAF& a, u16* As, u16* Bs,
                                              int bx, int by, int t) {
  const int bm0 = bx * 64, bn0 = by * 64;
  const int lane = t & 63, w = t >> 6;
  const int wm = (w >> 1) * 32, wn = (w & 1) * 32;
  const int sr = t >> 3, sc8 = t & 7, sc = sc8 * 8;
  int ar0 = bm0 + sr;      if (ar0 > a.M - 1) ar0 = a.M - 1;
  int ar1 = bm0 + sr + 32; if (ar1 > a.M - 1) ar1 = a.M - 1;
  const float* ap0 = a.Af + (long)ar0 * a.lda + sc;
  const float* ap1 = a.Af + (long)ar1 * a.lda + sc;
  const float* bp0 = a.Bf + (long)(bn0 + sr) * a.ldb + sc;
  const float* bp1 = a.Bf + (long)(bn0 + sr + 32) * a.ldb + sc;
  const int iA0 = sr * 64 + ((sc8 ^ (sr & 7)) << 3);
  const int iA1 = iA0 + 32 * 64;

  fv4 zero = {0.f, 0.f, 0.f, 0.f};
  fv4 acc00 = zero, acc01 = zero, acc10 = zero, acc11 = zero;
  const int r0 = lane & 15, kq8 = lane >> 4;
  const int nk = a.K >> 6;

  float4 xa0 = ld4(ap0), xa1 = ld4(ap0 + 4), xa2 = ld4(ap1), xa3 = ld4(ap1 + 4);
  float4 xb0 = ld4(bp0), xb1 = ld4(bp0 + 4), xb2 = ld4(bp1), xb3 = ld4(bp1 + 4);
  for (int kt = 0; kt < nk; ++kt) {
    __syncthreads();
    {
      const float v0[8] = {xa0.x, xa0.y, xa0.z, xa0.w, xa1.x, xa1.y, xa1.z, xa1.w};
      const float v1[8] = {xa2.x, xa2.y, xa2.z, xa2.w, xa3.x, xa3.y, xa3.z, xa3.w};
      const float v2[8] = {xb0.x, xb0.y, xb0.z, xb0.w, xb1.x, xb1.y, xb1.z, xb1.w};
      const float v3[8] = {xb2.x, xb2.y, xb2.z, xb2.w, xb3.x, xb3.y, xb3.z, xb3.w};
      *(uint4*)&As[iA0] = pack8(v0);
      *(uint4*)&As[iA1] = pack8(v1);
      *(uint4*)&Bs[iA0] = pack8(v2);
      *(uint4*)&Bs[iA1] = pack8(v3);
    }
    __syncthreads();
    if (kt + 1 < nk) {
      ap0 += 64; ap1 += 64; bp0 += 64; bp1 += 64;
      xa0 = ld4(ap0); xa1 = ld4(ap0 + 4); xa2 = ld4(ap1); xa3 = ld4(ap1 + 4);
      xb0 = ld4(bp0); xb1 = ld4(bp0 + 4); xb2 = ld4(bp1); xb3 = ld4(bp1 + 4);
    }
#pragma unroll
    for (int kc = 0; kc < 2; ++kc) {
      const int c8 = kq8 + 4 * kc;
      bh8 aa0 = lds_rd(As, wm + r0, c8);
      bh8 aa1 = lds_rd(As, wm + 16 + r0, c8);
      bh8 bb0 = lds_rd(Bs, wn + r0, c8);
      bh8 bb1 = lds_rd(Bs, wn + 16 + r0, c8);
      acc00 = __builtin_amdgcn_mfma_f32_16x16x32_bf16(aa0, bb0, acc00, 0, 0, 0);
      acc01 = __builtin_amdgcn_mfma_f32_16x16x32_bf16(aa0, bb1, acc01, 0, 0, 0);
      acc10 = __builtin_amdgcn_mfma_f32_16x16x32_bf16(aa1, bb0, acc10, 0, 0, 0);
      acc11 = __builtin_amdgcn_mfma_f32_16x16x32_bf16(aa1, bb1, acc11, 0, 0, 0);
    }
  }

  fv4 accs[2][2] = {{acc00, acc01}, {acc10, acc11}};
#pragma unroll
  for (int rb = 0; rb < 2; ++rb) {
#pragma unroll
    for (int cbl = 0; cbl < 2; ++cbl) {
#pragma unroll
      for (int j = 0; j < 4; ++j) {
        const int r = bm0 + wm + rb * 16 + (lane >> 4) * 4 + j;
        const int c = bn0 + wn + cbl * 16 + (lane & 15);
        if (r >= a.M) continue;
        const float v = accs[rb][cbl][j];
        if (a.epi == 1) {
          a.Cb[(long)r * a.ldc + c] = f2b(v);
        } else if (a.epi == 2) {
          const float x = tanhf(v + a.e0[c]);
          if (c < 512) a.Cf[(long)r * 512 + c] = x;
          else         a.Cf2[(long)r * 512 + (c - 512)] = x;
        } else {
          a.Cf[(long)r * a.ldc + c] = v + a.e0[c];
        }
      }
    }
  }
}

// ===========================================================================
// NEW: 128x128 f32-staging GEMM (G2). 4 waves, 4x4 16x16 subtiles/wave,
// BK=64, swizzled [128][64] LDS. Same K-slice order as 64x64 BK=64 core ->
// bitwise-identical accumulation. Epilogue: +bias, f32 store.
// ===========================================================================
struct G128 {
  const float* Af; const float* Bf;
  long lda, ldb;
  float* Cf;
  long ldc;
  int K;
  const float* bias;
};

__device__ __forceinline__ void gemm128_f32(const G128& a, u16* As, u16* Bs,
                                            int bx, int by, int t) {
  const int bm0 = bx * 128, bn0 = by * 128;
  const int lane = t & 63, w = t >> 6;
  const int qm = (w >> 1) * 64, qn = (w & 1) * 64;
  const int srb = t >> 3, sc8 = t & 7;
  const int r0 = lane & 15, kq8 = lane >> 4;
  const int nk = a.K >> 6;
  const int slot = (sc8 ^ (srb & 7)) << 3;  // (i*32+srb)&7 == srb&7

  fv4 acc[4][4];
#pragma unroll
  for (int mi = 0; mi < 4; ++mi)
#pragma unroll
    for (int ni = 0; ni < 4; ++ni) acc[mi][ni] = {0.f, 0.f, 0.f, 0.f};

  for (int kt = 0; kt < nk; ++kt) {
    __syncthreads();
    const long kof = (long)kt * 64 + sc8 * 8;
#pragma unroll
    for (int i = 0; i < 4; ++i) {
      const int r = i * 32 + srb;
      const float* pa = a.Af + (long)(bm0 + r) * a.lda + kof;
      const float4 x0 = ld4(pa), x1 = ld4(pa + 4);
      const float va[8] = {x0.x, x0.y, x0.z, x0.w, x1.x, x1.y, x1.z, x1.w};
      *(uint4*)&As[r * 64 + slot] = pack8(va);
      const float* pb = a.Bf + (long)(bn0 + r) * a.ldb + kof;
      const float4 y0 = ld4(pb), y1 = ld4(pb + 4);
      const float vb[8] = {y0.x, y0.y, y0.z, y0.w, y1.x, y1.y, y1.z, y1.w};
      *(uint4*)&Bs[r * 64 + slot] = pack8(vb);
    }
    __syncthreads();
#pragma unroll
    for (int kc = 0; kc < 2; ++kc) {
      const int c8 = kq8 + 4 * kc;
      bh8 af[4], bf[4];
#pragma unroll
      for (int mi = 0; mi < 4; ++mi) af[mi] = lds_rd(As, qm + mi * 16 + r0, c8);
#pragma unroll
      for (int ni = 0; ni < 4; ++ni) bf[ni] = lds_rd(Bs, qn + ni * 16 + r0, c8);
#pragma unroll
      for (int mi = 0; mi < 4; ++mi)
#pragma unroll
        for (int ni = 0; ni < 4; ++ni)
          acc[mi][ni] = __builtin_amdgcn_mfma_f32_16x16x32_bf16(af[mi], bf[ni], acc[mi][ni], 0, 0, 0);
    }
  }
#pragma unroll
  for (int mi = 0; mi < 4; ++mi)
#pragma unroll
    for (int ni = 0; ni < 4; ++ni)
#pragma unroll
      for (int j = 0; j < 4; ++j) {
        const int r = bm0 + qm + mi * 16 + (lane >> 4) * 4 + j;
        const int c = bn0 + qn + ni * 16 + (lane & 15);
        a.Cf[(long)r * a.ldc + c] = acc[mi][ni][j] + a.bias[c];
      }
}

// ===========================================================================
// NEW: Dual batched GEMM, 64(M) x 128(N) tile. EPI: 1 = s-epilogue, 2 = raw
// K1/K2. Same K-order as 64x64 dual -> bitwise-identical outputs.
// ===========================================================================
struct GA2 {
  const u16* A1; const u16* A2; const u16* B1; const u16* B2;
  long lda, ldb, sAz, sBz;
  float* Cf; float* Cf2; u16* Cb;
  long ldc, sCz;
  int M, K;
  const float* e1; const float* e2; const float* e3;
  const float* e4; const float* e5; const float* e6;
};

__device__ __forceinline__ void gemm2w_core(const GA2& a, u16* As1, u16* As2,
                                            u16* Bs1, u16* Bs2,
                                            int bx, int by, int bz, int t, int EPI) {
  const int z = bz;
  const int bm0 = bx * 64, bn0 = by * 128;
  const int lane = t & 63, w = t >> 6;
  const int wm = (w >> 1) * 32, wn = (w & 1) * 64;
  const u16* A1b = a.A1 + (long)z * a.sAz;
  const u16* A2b = a.A2 + (long)z * a.sAz;
  const u16* B1b = a.B1 + (long)z * a.sBz;
  const u16* B2b = a.B2 + (long)z * a.sBz;

  const int srb = t >> 3, sc8 = t & 7, sc = sc8 * 8;
  const int slot = (sc8 ^ (srb & 7)) << 3;
  const int iA0 = srb * 64 + slot, iA1 = iA0 + 32 * 64;
  const u16* a1p0 = A1b + (long)(bm0 + srb) * a.lda + sc;
  const u16* a1p1 = A1b + (long)(bm0 + srb + 32) * a.lda + sc;
  const u16* a2p0 = A2b + (long)(bm0 + srb) * a.lda + sc;
  const u16* a2p1 = A2b + (long)(bm0 + srb + 32) * a.lda + sc;
  const u16* b1p[4]; const u16* b2p[4];
#pragma unroll
  for (int i = 0; i < 4; ++i) {
    b1p[i] = B1b + (long)(bn0 + i * 32 + srb) * a.ldb + sc;
    b2p[i] = B2b + (long)(bn0 + i * 32 + srb) * a.ldb + sc;
  }

  fv4 p[2][4], q[2][4];
#pragma unroll
  for (int mi = 0; mi < 2; ++mi)
#pragma unroll
    for (int ni = 0; ni < 4; ++ni) { p[mi][ni] = {0.f,0.f,0.f,0.f}; q[mi][ni] = {0.f,0.f,0.f,0.f}; }

  const int r0 = lane & 15, kq8 = lane >> 4;
  const int nk = a.K >> 6;

  uint4 a1v0 = *(const uint4*)a1p0, a1v1 = *(const uint4*)a1p1;
  uint4 a2v0 = *(const uint4*)a2p0, a2v1 = *(const uint4*)a2p1;
  uint4 b1v[4], b2v[4];
#pragma unroll
  for (int i = 0; i < 4; ++i) { b1v[i] = *(const uint4*)b1p[i]; b2v[i] = *(const uint4*)b2p[i]; }

  for (int kt = 0; kt < nk; ++kt) {
    __syncthreads();
    *(uint4*)&As1[iA0] = a1v0; *(uint4*)&As1[iA1] = a1v1;
    *(uint4*)&As2[iA0] = a2v0; *(uint4*)&As2[iA1] = a2v1;
#pragma unroll
    for (int i = 0; i < 4; ++i) {
      *(uint4*)&Bs1[iA0 + i * 2048] = b1v[i];
      *(uint4*)&Bs2[iA0 + i * 2048] = b2v[i];
    }
    __syncthreads();
    if (kt + 1 < nk) {
      a1p0 += 64; a1p1 += 64; a2p0 += 64; a2p1 += 64;
      a1v0 = *(const uint4*)a1p0; a1v1 = *(const uint4*)a1p1;
      a2v0 = *(const uint4*)a2p0; a2v1 = *(const uint4*)a2p1;
#pragma unroll
      for (int i = 0; i < 4; ++i) {
        b1p[i] += 64; b2p[i] += 64;
        b1v[i] = *(const uint4*)b1p[i]; b2v[i] = *(const uint4*)b2p[i];
      }
    }
#pragma unroll
    for (int kc = 0; kc < 2; ++kc) {
      const int c8 = kq8 + 4 * kc;
      bh8 x0 = lds_rd(As1, wm + r0, c8);
      bh8 x1 = lds_rd(As1, wm + 16 + r0, c8);
      bh8 y[4];
#pragma unroll
      for (int ni = 0; ni < 4; ++ni) y[ni] = lds_rd(Bs1, wn + ni * 16 + r0, c8);
#pragma unroll
      for (int ni = 0; ni < 4; ++ni) {
        p[0][ni] = __builtin_amdgcn_mfma_f32_16x16x32_bf16(x0, y[ni], p[0][ni], 0, 0, 0);
        p[1][ni] = __builtin_amdgcn_mfma_f32_16x16x32_bf16(x1, y[ni], p[1][ni], 0, 0, 0);
      }
      bh8 u0 = lds_rd(As2, wm + r0, c8);
      bh8 u1 = lds_rd(As2, wm + 16 + r0, c8);
      bh8 v[4];
#pragma unroll
      for (int ni = 0; ni < 4; ++ni) v[ni] = lds_rd(Bs2, wn + ni * 16 + r0, c8);
#pragma unroll
      for (int ni = 0; ni < 4; ++ni) {
        q[0][ni] = __builtin_amdgcn_mfma_f32_16x16x32_bf16(u0, v[ni], q[0][ni], 0, 0, 0);
        q[1][ni] = __builtin_amdgcn_mfma_f32_16x16x32_bf16(u1, v[ni], q[1][ni], 0, 0, 0);
      }
    }
  }

#pragma unroll
  for (int mi = 0; mi < 2; ++mi)
#pragma unroll
    for (int ni = 0; ni < 4; ++ni)
#pragma unroll
      for (int j = 0; j < 4; ++j) {
        const int r = bm0 + wm + mi * 16 + (lane >> 4) * 4 + j;
        const int c = bn0 + wn + ni * 16 + (lane & 15);
        const float v1 = p[mi][ni][j];
        const float v2 = q[mi][ni][j];
        if (EPI == 2) {  // raw K1/K2
          const long idx = (long)z * a.sCz + (long)r * a.ldc + c;
          a.Cf[idx] = v1;
          a.Cf2[idx] = v2;
        } else {  // s: v1=T1, v2=T2
          const int lh = z * 256 + r;
          const int bl = z * 32 + (r >> 3);
          const float G2d = a.e1[c], B2d = a.e2[c];
          const float gv = a.e3[(long)bl * 512 + c];
          const float bev = a.e4[(long)bl * 512 + c];
          const float sv = v1 + B2d + G2d * (gv * v2 + bev * a.e5[lh] - a.e6[lh]);
          a.Cb[(long)z * a.sCz + (long)r * a.ldc + c] = f2b(sv);
        }
      }
}

// ===========================================================================
// Elementwise / transpose units (verified)
// ===========================================================================
__device__ __forceinline__ void tpf32_unit(const float* src, long lds, u16* dst, long ldd,
                                           int tr, int tc, int t, float T[64][65]) {
  const int c = t & 63, rg = t >> 6;
#pragma unroll 4
  for (int i = 0; i < 16; ++i) {
    const int r = rg + 4 * i;
    T[r][c] = src[(long)(tr * 64 + r) * lds + tc * 64 + c];
  }
  __syncthreads();
#pragma unroll 4
  for (int i = 0; i < 16; ++i) {
    const int r = rg + 4 * i;
    dst[(long)(tc * 64 + r) * ldd + tr * 64 + c] = f2b(T[c][r]);
  }
}

__device__ __forceinline__ void tpb16_unit(const u16* src, u16* dst, int b, int w32,
                                           int t, float T[64][65]) {
  const int tr = w32 >> 3, tc = w32 & 7;
  const u16* s = src + (long)b * 131072;
  u16* d = dst + (long)b * 131072;
  const int c = t & 63, rg = t >> 6;
#pragma unroll 4
  for (int i = 0; i < 16; ++i) {
    const int r = rg + 4 * i;
    T[r][c] = b2f(s[(long)(tr * 64 + r) * 512 + tc * 64 + c]);
  }
  __syncthreads();
#pragma unroll 4
  for (int i = 0; i < 16; ++i) {
    const int r = rg + 4 * i;
    d[(long)(tc * 64 + r) * 256 + tr * 64 + c] = f2b(T[c][r]);
  }
}

__device__ __forceinline__ void cvt_unit(const float* s, u16* d, long blk, int t) {
  const long idx = blk * 2048 + t * 8;
  const float4 x0 = ld4(s + idx), x1 = ld4(s + idx + 4);
  const float v[8] = {x0.x, x0.y, x0.z, x0.w, x1.x, x1.y, x1.z, x1.w};
  *(uint4*)(d + idx) = pack8(v);
}

__device__ __forceinline__ void ln_unit(const FA& f, int u, int t) {
  const int lane = t & 63, e = lane * 8;
  const int row = u * 4 + (t >> 6);
  const float* p = f.condpre + (long)row * 512 + e;
  const float4 x0 = ld4(p), x1 = ld4(p + 4);
  float v[8] = {x0.x, x0.y, x0.z, x0.w, x1.x, x1.y, x1.z, x1.w};
  float s = 0.f, sq = 0.f;
#pragma unroll
  for (int i = 0; i < 8; ++i) { s += v[i]; sq += v[i] * v[i]; }
#pragma unroll
  for (int m = 1; m < 64; m <<= 1) { s += __shfl_xor(s, m); sq += __shfl_xor(sq, m); }
  const float mu = s * (1.f / 512.f);
  const float iv = rsqrtf(sq * (1.f / 512.f) - mu * mu + LN_EPS);
  const float4 g0 = ld4(f.ln1g + e), g1 = ld4(f.ln1g + e + 4);
  const float4 b0 = ld4(f.ln1b + e), b1 = ld4(f.ln1b + e + 4);
  const float gg[8] = {g0.x, g0.y, g0.z, g0.w, g1.x, g1.y, g1.z, g1.w};
  const float bb[8] = {b0.x, b0.y, b0.z, b0.w, b1.x, b1.y, b1.z, b1.w};
  float o[8], osq[8];
#pragma unroll
  for (int i = 0; i < 8; ++i) {
    o[i] = (v[i] - mu) * iv * gg[i] + bb[i];
    osq[i] = o[i] * o[i];
  }
  *(uint4*)(f.cb_bf + (long)row * 512 + e) = pack8(o);
  *(uint4*)(f.cbsq_bf + (long)row * 512 + e) = pack8(osq);
}

__device__ __forceinline__ void a96_unit(const FA& f, int u, int t) {
  const int lane = t & 63, e = lane * 8;
  const int bl = u * 4 + (t >> 6);
  const int b = bl >> 5, l = bl & 31;
  const float4 ga0 = ld4(f.gam + (long)bl * 512 + e), ga1 = ld4(f.gam + (long)bl * 512 + e + 4);
  const float4 be0 = ld4(f.bet + (long)bl * 512 + e), be1 = ld4(f.bet + (long)bl * 512 + e + 4);
  const float gv[8] = {ga0.x, ga0.y, ga0.z, ga0.w, ga1.x, ga1.y, ga1.z, ga1.w};
  const float bv[8] = {be0.x, be0.y, be0.z, be0.w, be1.x, be1.y, be1.z, be1.w};
  float gg[8], gb[8]; float s1 = 0.f, s2 = 0.f;
#pragma unroll
  for (int i = 0; i < 8; ++i) {
    gg[i] = gv[i] * gv[i]; gb[i] = gv[i] * bv[i];
    s1 += bv[i]; s2 += bv[i] * bv[i];
  }
  const long basei = ((long)b * 96 + l) * 512 + e;
  *(uint4*)(f.A96_bf + basei) = pack8(gv);
  *(uint4*)(f.A96_bf + basei + 32 * 512) = pack8(gb);
  *(uint4*)(f.A96_bf + basei + 64 * 512) = pack8(gg);
#pragma unroll
  for (int m = 1; m < 64; m <<= 1) { s1 += __shfl_xor(s1, m); s2 += __shfl_xor(s2, m); }
  if (lane == 0) { f.sum_be[bl] = s1; f.sum_be2[bl] = s2; }
}

__device__ __forceinline__ void csum_unit(const FA& f, int u, int t) {
  const int lane = t & 63, e = lane * 8;
  const int lh = u * 4 + (t >> 6);
  const int bl = lh >> 3;
  const uint4 up = *(const uint4*)(f.u_bf + (long)lh * 512 + e);
  const u16* us = (const u16*)&up;
  const float4 be0 = ld4(f.bet + (long)bl * 512 + e), be1 = ld4(f.bet + (long)bl * 512 + e + 4);
  const float4 G0 = ld4(f.ln2g + e), G1 = ld4(f.ln2g + e + 4);
  const float4 B0 = ld4(f.ln2b + e), B1 = ld4(f.ln2b + e + 4);
  const float bv[8] = {be0.x, be0.y, be0.z, be0.w, be1.x, be1.y, be1.z, be1.w};
  const float Gv[8] = {G0.x, G0.y, G0.z, G0.w, G1.x, G1.y, G1.z, G1.w};
  const float Bv[8] = {B0.x, B0.y, B0.z, B0.w, B1.x, B1.y, B1.z, B1.w};
  float a2 = 0.f, a3 = 0.f, a4 = 0.f;
#pragma unroll
  for (int i = 0; i < 8; ++i) {
    const float uu = b2f(us[i]);
    const float t1 = Gv[i] * uu;
    a2 += bv[i] * t1; a3 += t1; a4 += Bv[i] * uu;
  }
#pragma unroll
  for (int m = 1; m < 64; m <<= 1) {
    a2 += __shfl_xor(a2, m); a3 += __shfl_xor(a3, m); a4 += __shfl_xor(a4, m);
  }
  if (lane == 0) { f.c2[lh] = a2; f.c3[lh] = a3; f.c4[lh] = a4; }
}

__device__ __forceinline__ void softmax2_unit(const FA& f, int u, int t) {
  const int lane = t & 63, e = lane * 4;
  const int lh = u * 4 + (t >> 6);
  const int b = lh >> 8, l = (lh >> 3) & 31, bl = lh >> 3;
  const float4 k1 = ld4(f.K1 + (long)lh * 256 + e);
  const float4 k2 = ld4(f.K2 + (long)lh * 256 + e);
  const float* Pb = f.P + ((long)b * 96 + l) * 256 + e;
  const float4 p0 = ld4(Pb), pgb = ld4(Pb + 32 * 256), pg2 = ld4(Pb + 64 * 256);
  const float sbe = f.sum_be[bl], sbe2 = f.sum_be2[bl];
  const float C2 = f.c2[lh], C3 = f.c3[lh], C4 = f.c4[lh];
  const float k1s[4] = {k1.x, k1.y, k1.z, k1.w};
  const float k2s[4] = {k2.x, k2.y, k2.z, k2.w};
  const float p0s[4] = {p0.x, p0.y, p0.z, p0.w};
  const float pgbs[4] = {pgb.x, pgb.y, pgb.z, pgb.w};
  const float pg2s[4] = {pg2.x, pg2.y, pg2.z, pg2.w};
  float mu[4], iv[4], lgs[4];
#pragma unroll
  for (int i = 0; i < 4; ++i) {
    mu[i] = (p0s[i] + sbe) * (1.f / 512.f);
    const float msq = (pg2s[i] + 2.f * pgbs[i] + sbe2) * (1.f / 512.f);
    iv[i] = rsqrtf(msq - mu[i] * mu[i] + LN_EPS);
    lgs[i] = k1s[i] + C4 + iv[i] * (k2s[i] + C2 - mu[i] * C3);
  }
  float mx = fmaxf(fmaxf(lgs[0], lgs[1]), fmaxf(lgs[2], lgs[3]));
#pragma unroll
  for (int m = 1; m < 64; m <<= 1) mx = fmaxf(mx, __shfl_xor(mx, m));
  float ex[4]; float z = 0.f;
#pragma unroll
  for (int i = 0; i < 4; ++i) { ex[i] = expf(lgs[i] - mx); z += ex[i]; }
#pragma unroll
  for (int m = 1; m < 64; m <<= 1) z += __shfl_xor(z, m);
  const float rz = 1.f / z;
  float wv[4], w1v[4]; float s1 = 0.f, s2 = 0.f;
#pragma unroll
  for (int i = 0; i < 4; ++i) {
    wv[i] = ex[i] * rz;
    w1v[i] = wv[i] * iv[i];
    s1 += w1v[i]; s2 += w1v[i] * mu[i];
  }
  uint2 wp, w1p;
  wp.x = pk2(wv[0], wv[1]); wp.y = pk2(wv[2], wv[3]);
  w1p.x = pk2(w1v[0], w1v[1]); w1p.y = pk2(w1v[2], w1v[3]);
  *(uint2*)(f.w_bf + (long)lh * 256 + e) = wp;
  *(uint2*)(f.W1_bf + (long)lh * 256 + e) = w1p;
#pragma unroll
  for (int m = 1; m < 64; m <<= 1) { s1 += __shfl_xor(s1, m); s2 += __shfl_xor(s2, m); }
  if (lane == 0) { f.S1[lh] = s1; f.S2[lh] = s2; }
}

// ===========================================================================
// Phase kernels (7 dispatches)
// ===========================================================================
// A: G2-128(128) + G1a(128) + G1b(64) + k cvt(1024) + Wv(128) + Wfc(128)
//    + WkT(64) + kT(512) = 2176
__global__ __launch_bounds__(256) void pA_k(FA f) {
  __shared__ __align__(16) char smem[32768];
  float (*T)[65] = (float(*)[65])smem;
  const int u = blockIdx.x, t = threadIdx.x;
  if (u < 128) {
    u16* As = (u16*)smem; u16* Bs = (u16*)(smem + 16384);
    G128 a = {}; a.Af = f.k; a.Bf = f.Wvp; a.lda = 512; a.ldb = 512;
    a.Cf = f.condpre; a.ldc = 512; a.K = 512; a.bias = f.bvp;
    gemm128_f32(a, As, Bs, u % 32, u / 32, t);
  } else if (u < 256) {
    u16* As = (u16*)smem; u16* Bs = (u16*)(smem + 8192);
    const int r = u - 128;
    GAF a = {}; a.Af = f.q; a.Bf = f.Wg; a.lda = 512; a.ldb = 512;
    a.Cf = f.gam; a.Cf2 = f.bet; a.ldc = 512; a.M = 512; a.K = 512; a.epi = 2; a.e0 = f.bg;
    gemm_core_f32(a, As, Bs, r % 8, r / 8, t);
  } else if (u < 320) {
    u16* As = (u16*)smem; u16* Bs = (u16*)(smem + 8192);
    const int r = u - 256;
    GAF a = {}; a.Af = f.q; a.Bf = f.Wq; a.lda = 512; a.ldb = 512;
    a.Cb = f.qh_bf; a.ldc = 512; a.M = 512; a.K = 512; a.epi = 1;
    gemm_core_f32(a, As, Bs, r % 8, r / 8, t);
  } else if (u < 1344) {
    cvt_unit(f.k, f.k_bf, u - 320, t);
  } else if (u < 1472) {
    cvt_unit(f.Wv, f.Wv_bf, u - 1344, t);
  } else if (u < 1600) {
    cvt_unit(f.Wfc, f.Wfc_bf, u - 1472, t);
  } else if (u < 1664) {
    const int tt = u - 1600;
    tpf32_unit(f.Wk, 512, f.WkT_bf, 512, tt >> 3, tt & 7, t, T);
  } else {
    const int tt = u - 1664;
    const int b = tt >> 5, w32 = tt & 31;
    tpf32_unit(f.k + (long)b * 131072, 512, f.kT_bf + (long)b * 131072, 256,
               w32 >> 3, w32 & 7, t, T);
  }
}

// B: LN(1024) + A96(128) + Gu·w1(512) = 1664
__global__ __launch_bounds__(256) void pB_k(FA f) {
  __shared__ __align__(16) char smem[16384];
  u16* As = (u16*)smem;
  u16* Bs = (u16*)(smem + 8192);
  const int u = blockIdx.x, t = threadIdx.x;
  if (u < 1024) {
    ln_unit(f, u, t);
  } else if (u < 1152) {
    a96_unit(f, u - 1024, t);
  } else {
    const int r = u - 1152;
    GA a = {}; a.A = f.qh_bf; a.lda = 512; a.sAz = 64;
    a.B = f.WkT_bf; a.ldb = 512; a.sBz = 64;
    a.Cb = f.u_bf; a.Cb2 = f.w1_bf; a.ldc = 512; a.M = 512; a.K = 64; a.epi = 6;
    a.e0 = f.gam; a.e1 = f.ln2g;
    gemm_core(a, As, Bs, r % 8, (r / 8) % 8, r / 64, t);
  }
}

// C: GP(128) + cbT(512) + csum(1024) + GK-raw wide(128) = 1792
__global__ __launch_bounds__(256) void pC_k(FA f) {
  __shared__ __align__(16) char smem[49152];
  const int u = blockIdx.x, t = threadIdx.x;
  if (u < 128) {
    u16* As = (u16*)smem; u16* Bs = (u16*)(smem + 8192);
    GA a = {}; a.A = f.A96_bf; a.lda = 512; a.sAz = 96 * 512;
    a.B = f.cb_bf; a.Balt = f.cbsq_bf; a.ldb = 512; a.sBz = 256 * 512;
    a.Cf = f.P; a.ldc = 256; a.sCz = 96 * 256; a.M = 96; a.K = 512; a.epi = 0;
    gemm_core(a, As, Bs, u % 2, (u / 2) % 4, u / 8, t);
  } else if (u < 640) {
    float (*T)[65] = (float(*)[65])smem;
    const int tt = u - 128;
    tpb16_unit(f.cb_bf, f.cbT_bf, tt >> 5, tt & 31, t, T);
  } else if (u < 1664) {
    csum_unit(f, u - 640, t);
  } else {
    const int r = u - 1664;
    u16* As1 = (u16*)smem; u16* As2 = (u16*)(smem + 8192);
    u16* Bs1 = (u16*)(smem + 16384); u16* Bs2 = (u16*)(smem + 32768);
    GA2 d = {};
    d.A1 = f.u_bf; d.A2 = f.w1_bf; d.B1 = f.k_bf; d.B2 = f.cb_bf;
    d.lda = 512; d.ldb = 512; d.sAz = 256 * 512; d.sBz = 256 * 512;
    d.Cf = f.K1; d.Cf2 = f.K2; d.ldc = 256; d.sCz = 256 * 256; d.M = 256; d.K = 512;
    gemm2w_core(d, As1, As2, Bs1, Bs2, r % 4, (r / 4) % 2, r / 8, t, 2);
  }
}

// D: softmax + logits assembly (1024)
__global__ __launch_bounds__(256) void pD_k(FA f) {
  softmax2_unit(f, blockIdx.x, threadIdx.x);
}

// E: GT wide (256)
__global__ __launch_bounds__(256) void pE_k(FA f) {
  __shared__ __align__(16) char smem[49152];
  u16* As1 = (u16*)smem; u16* As2 = (u16*)(smem + 8192);
  u16* Bs1 = (u16*)(smem + 16384); u16* Bs2 = (u16*)(smem + 32768);
  const int u = blockIdx.x, t = threadIdx.x;
  GA2 d = {};
  d.A1 = f.w_bf; d.A2 = f.W1_bf; d.B1 = f.kT_bf; d.B2 = f.cbT_bf;
  d.lda = 256; d.ldb = 256; d.sAz = 256 * 256; d.sBz = 512 * 256;
  d.Cb = f.s_bf; d.ldc = 512; d.sCz = 256 * 512; d.M = 256; d.K = 256;
  d.e1 = f.ln2g; d.e2 = f.ln2b; d.e3 = f.gam; d.e4 = f.bet; d.e5 = f.S1; d.e6 = f.S2;
  gemm2w_core(d, As1, As2, Bs1, Bs2, u % 4, (u / 4) % 4, u / 16, t, 1);
}

// F: attn = s_h @ Wv_h^T (64)
__global__ __launch_bounds__(256) void pF_k(FA f) {
  __shared__ __align__(16) char smem[16384];
  u16* As = (u16*)smem; u16* Bs = (u16*)(smem + 8192);
  const int u = blockIdx.x, t = threadIdx.x;
  GA a = {}; a.A = f.s_bf; a.lda = 4096; a.sAz = 512;
  a.B = f.Wv_bf; a.ldb = 512; a.sBz = 64 * 512;
  a.Cb = f.attn_bf; a.ldc = 512; a.sCz = 64; a.M = 512; a.K = 512; a.epi = 1;
  gemm_core(a, As, Bs, u % 8, 0, u / 8, t);
}

// G: out = attn @ Wfc^T (64)
__global__ __launch_bounds__(256) void pG_k(FA f) {
  __shared__ __align__(16) char smem[16384];
  u16* As = (u16*)smem; u16* Bs = (u16*)(smem + 8192);
  const int u = blockIdx.x, t = threadIdx.x;
  GA a = {}; a.A = f.attn_bf; a.lda = 512;
  a.B = f.Wfc_bf; a.ldb = 512;
  a.Cf = f.out; a.ldc = 512; a.M = 512; a.K = 512; a.epi = 0;
  gemm_core(a, As, Bs, u % 8, u / 8, 0, t);
}

}  // namespace

extern "C" void kernel_launch(void* const* d_in, const int* in_sizes, int n_in,
                              void* d_out, int out_size, void* d_ws, size_t ws_size,
                              hipStream_t stream) {
  (void)in_sizes; (void)n_in; (void)out_size;
  FA fa;
  fa.q    = (const float*)d_in[0];
  fa.k    = (const float*)d_in[1];
  fa.Wq   = (const float*)d_in[3];
  fa.Wk   = (const float*)d_in[4];
  fa.Wv   = (const float*)d_in[5];
  fa.Wfc  = (const float*)d_in[6];
  fa.Wg   = (const float*)d_in[7];
  fa.bg   = (const float*)d_in[8];
  fa.Wvp  = (const float*)d_in[9];
  fa.bvp  = (const float*)d_in[10];
  fa.ln1g = (const float*)d_in[11];
  fa.ln1b = (const float*)d_in[12];
  fa.ln2g = (const float*)d_in[13];
  fa.ln2b = (const float*)d_in[14];
  fa.out  = (float*)d_out;

  char* base = (char*)d_ws;
  size_t off = 0;
  auto au16 = [&](size_t n) -> u16* {
    u16* p = (u16*)(base + off); off = (off + n * 2 + 255) & ~(size_t)255; return p;
  };
  auto af32 = [&](size_t n) -> float* {
    float* p = (float*)(base + off); off = (off + n * 4 + 255) & ~(size_t)255; return p;
  };
  (void)au16(262144);               // layout parity (unused)
  (void)au16(524288);
  (void)au16(262144);
  (void)au16(262144);
  fa.WkT_bf  = au16(262144);
  fa.Wv_bf   = au16(262144);
  fa.Wfc_bf  = au16(262144);
  fa.k_bf    = au16(2097152);
  fa.kT_bf   = au16(2097152);
  fa.qh_bf   = au16(262144);
  fa.gam     = af32(262144);
  fa.bet     = af32(262144);
  fa.condpre = af32(2097152);       // K1 = first half, K2 = second half (post-LN)
  fa.cb_bf   = au16(2097152);
  fa.cbT_bf  = au16(2097152);
  fa.u_bf    = au16(2097152);
  fa.w1_bf   = au16(2097152);
  fa.c2      = af32(4096);
  fa.c3      = af32(4096);
  fa.c4      = af32(4096);
  fa.A96_bf  = au16(16 * 96 * 512);
  fa.sum_be  = af32(512);
  fa.sum_be2 = af32(512);
  fa.P       = af32(16 * 96 * 256);
  float* sbuf   = af32(1048576);
  float* logits = af32(1048576);
  fa.w_bf    = au16(1048576);
  fa.W1_bf   = au16(1048576);
  fa.S1      = af32(4096);
  fa.S2      = af32(4096);
  fa.attn_bf = au16(262144);
  const size_t need = off;
  fa.s_bf    = (u16*)sbuf;
  fa.cbsq_bf = (u16*)logits;
  fa.K1      = fa.condpre;          // condpre dead after LN (phase B)
  fa.K2      = fa.condpre + 1048576;

  if (ws_size < need) return;

  const dim3 blk(256);
  pA_k<<<dim3(2176), blk, 0, stream>>>(fa);
  pB_k<<<dim3(1664), blk, 0, stream>>>(fa);
  pC_k<<<dim3(1792), blk, 0, stream>>>(fa);
  pD_k<<<dim3(1024), blk, 0, stream>>>(fa);
  pE_k<<<dim3(256),  blk, 0, stream>>>(fa);
  pF_k<<<dim3(64),   blk, 0, stream>>>(fa);
  pG_k<<<dim3(64),   blk, 0, stream>>>(fa);
}

// Round 9
// 112.173 us; speedup vs baseline: 1.0828x; 1.0828x over previous
//
#include <hip/hip_runtime.h>
#include <math.h>

namespace {
constexpr float LN_EPS = 1e-5f;

typedef unsigned short u16;
typedef __attribute__((ext_vector_type(8))) short bh8;
typedef __attribute__((ext_vector_type(4))) float fv4;

__device__ __forceinline__ float4 ld4(const float* p) { return *reinterpret_cast<const float4*>(p); }

__device__ __forceinline__ float b2f(u16 x) {
  union { float f; unsigned u; } c; c.u = ((unsigned)x) << 16; return c.f;
}
__device__ __forceinline__ u16 f2b(float f) {  // RTN-even
  union { float f; unsigned u; } c; c.f = f;
  unsigned u = c.u;
  u += 0x7FFFu + ((u >> 16) & 1u);
  return (u16)(u >> 16);
}
__device__ __forceinline__ unsigned pk2(float a, float b) {
  return (unsigned)f2b(a) | ((unsigned)f2b(b) << 16);
}
__device__ __forceinline__ uint4 pack8(const float* v) {
  uint4 r; r.x = pk2(v[0], v[1]); r.y = pk2(v[2], v[3]); r.z = pk2(v[4], v[5]); r.w = pk2(v[6], v[7]);
  return r;
}

// XOR-swizzled LDS tile access: [R][64] u16, 16B slots, c8 ^= row&7
__device__ __forceinline__ bh8 lds_rd(const u16* S, int row, int c8) {
  return *(const bh8*)&S[row * 64 + ((c8 ^ (row & 7)) << 3)];
}

struct FA {
  const float *q, *k, *Wq, *Wk, *Wv, *Wfc, *Wg, *bg, *Wvp, *bvp;
  const float *ln1g, *ln1b, *ln2g, *ln2b;
  float* out;
  u16 *WkT_bf, *Wv_bf, *Wfc_bf, *k_bf, *kT_bf, *qh_bf;
  float *gam, *bet, *condpre;
  u16 *cb_bf, *cbT_bf, *u_bf, *w1_bf;
  float *c2, *c3, *c4;
  u16* A96_bf;
  float *sum_be, *sum_be2, *P;
  u16* s_bf;
  u16 *cbsq_bf;
  u16* attn_bf;
  float *K1, *K2;
};

// ===========================================================================
// bf16 GEMM core 64x64 (verified). epi: 0 f32, 1 bf16, 5 u-remap,
// 6 u-remap + fused w1
// ===========================================================================
struct GA {
  const u16* A; const u16* B; const u16* Balt;
  long lda, ldb, sAz, sBz;
  float* Cf; u16* Cb; u16* Cb2;
  long ldc, sCz;
  int M, K, epi;
  const float* e0; const float* e1;
};

__device__ __forceinline__ void gemm_core(const GA& a, u16* As, u16* Bs,
                                          int bx, int by, int bz, int t) {
  const int z = bz;
  const int bm0 = bx * 64, bn0 = by * 64;
  const int lane = t & 63, w = t >> 6;
  const int wm = (w >> 1) * 32, wn = (w & 1) * 32;
  const u16* Ab = a.A + (long)z * a.sAz;
  const u16* Bbase = (a.Balt != nullptr && bm0 >= 64) ? a.Balt : a.B;
  const u16* Bb = Bbase + (long)z * a.sBz;

  const int sr = t >> 3, sc8 = t & 7, sc = sc8 * 8;
  int ar0 = bm0 + sr;      if (ar0 > a.M - 1) ar0 = a.M - 1;
  int ar1 = bm0 + sr + 32; if (ar1 > a.M - 1) ar1 = a.M - 1;
  const u16* ap0 = Ab + (long)ar0 * a.lda + sc;
  const u16* ap1 = Ab + (long)ar1 * a.lda + sc;
  const u16* bp0 = Bb + (long)(bn0 + sr) * a.ldb + sc;
  const u16* bp1 = Bb + (long)(bn0 + sr + 32) * a.ldb + sc;
  const int iA0 = sr * 64 + ((sc8 ^ (sr & 7)) << 3);
  const int iA1 = iA0 + 32 * 64;

  fv4 zero = {0.f, 0.f, 0.f, 0.f};
  fv4 acc00 = zero, acc01 = zero, acc10 = zero, acc11 = zero;
  const int r0 = lane & 15, kq8 = lane >> 4;
  const int nk = a.K >> 6;

  uint4 av0 = *(const uint4*)ap0, av1 = *(const uint4*)ap1;
  uint4 bv0 = *(const uint4*)bp0, bv1 = *(const uint4*)bp1;
  for (int kt = 0; kt < nk; ++kt) {
    __syncthreads();
    *(uint4*)&As[iA0] = av0; *(uint4*)&As[iA1] = av1;
    *(uint4*)&Bs[iA0] = bv0; *(uint4*)&Bs[iA1] = bv1;
    __syncthreads();
    if (kt + 1 < nk) {
      ap0 += 64; ap1 += 64; bp0 += 64; bp1 += 64;
      av0 = *(const uint4*)ap0; av1 = *(const uint4*)ap1;
      bv0 = *(const uint4*)bp0; bv1 = *(const uint4*)bp1;
    }
#pragma unroll
    for (int kc = 0; kc < 2; ++kc) {
      const int c8 = kq8 + 4 * kc;
      bh8 aa0 = lds_rd(As, wm + r0, c8);
      bh8 aa1 = lds_rd(As, wm + 16 + r0, c8);
      bh8 bb0 = lds_rd(Bs, wn + r0, c8);
      bh8 bb1 = lds_rd(Bs, wn + 16 + r0, c8);
      acc00 = __builtin_amdgcn_mfma_f32_16x16x32_bf16(aa0, bb0, acc00, 0, 0, 0);
      acc01 = __builtin_amdgcn_mfma_f32_16x16x32_bf16(aa0, bb1, acc01, 0, 0, 0);
      acc10 = __builtin_amdgcn_mfma_f32_16x16x32_bf16(aa1, bb0, acc10, 0, 0, 0);
      acc11 = __builtin_amdgcn_mfma_f32_16x16x32_bf16(aa1, bb1, acc11, 0, 0, 0);
    }
  }

  fv4 accs[2][2] = {{acc00, acc01}, {acc10, acc11}};
#pragma unroll
  for (int rb = 0; rb < 2; ++rb) {
#pragma unroll
    for (int cbl = 0; cbl < 2; ++cbl) {
#pragma unroll
      for (int j = 0; j < 4; ++j) {
        const int r = bm0 + wm + rb * 16 + (lane >> 4) * 4 + j;
        const int c = bn0 + wn + cbl * 16 + (lane & 15);
        if (r >= a.M) continue;
        const float v = accs[rb][cbl][j];
        if (a.epi == 0) {
          a.Cf[(long)z * a.sCz + (long)r * a.ldc + c] = v;
        } else if (a.epi == 1) {
          a.Cb[(long)z * a.sCz + (long)r * a.ldc + c] = f2b(v);
        } else if (a.epi == 5) {
          a.Cb[((long)r * 8 + z) * a.ldc + c] = f2b(v * 0.125f);
        } else {  // 6: u remap + fused w1
          const u16 ub = f2b(v * 0.125f);
          const long orow = (long)r * 8 + z;
          a.Cb[orow * 512 + c] = ub;
          const float uu = b2f(ub);
          const float t1 = a.e1[c] * uu;
          a.Cb2[orow * 512 + c] = f2b(a.e0[(long)r * 512 + c] * t1);
        }
      }
    }
  }
}

// ===========================================================================
// f32-staging GEMM core 64x64 (verified). epi: 1 bf16, 2 film, 4 +bias
// ===========================================================================
struct GAF {
  const float* Af; const float* Bf;
  long lda, ldb;
  float* Cf; u16* Cb; float* Cf2;
  long ldc;
  int M, K, epi;
  const float* e0;
};

__device__ __forceinline__ void gemm_core_f32(const GAF& a, u16* As, u16* Bs,
                                              int bx, int by, int t) {
  const int bm0 = bx * 64, bn0 = by * 64;
  const int lane = t & 63, w = t >> 6;
  const int wm = (w >> 1) * 32, wn = (w & 1) * 32;
  const int sr = t >> 3, sc8 = t & 7, sc = sc8 * 8;
  int ar0 = bm0 + sr;      if (ar0 > a.M - 1) ar0 = a.M - 1;
  int ar1 = bm0 + sr + 32; if (ar1 > a.M - 1) ar1 = a.M - 1;
  const float* ap0 = a.Af + (long)ar0 * a.lda + sc;
  const float* ap1 = a.Af + (long)ar1 * a.lda + sc;
  const float* bp0 = a.Bf + (long)(bn0 + sr) * a.ldb + sc;
  const float* bp1 = a.Bf + (long)(bn0 + sr + 32) * a.ldb + sc;
  const int iA0 = sr * 64 + ((sc8 ^ (sr & 7)) << 3);
  const int iA1 = iA0 + 32 * 64;

  fv4 zero = {0.f, 0.f, 0.f, 0.f};
  fv4 acc00 = zero, acc01 = zero, acc10 = zero, acc11 = zero;
  const int r0 = lane & 15, kq8 = lane >> 4;
  const int nk = a.K >> 6;

  float4 xa0 = ld4(ap0), xa1 = ld4(ap0 + 4), xa2 = ld4(ap1), xa3 = ld4(ap1 + 4);
  float4 xb0 = ld4(bp0), xb1 = ld4(bp0 + 4), xb2 = ld4(bp1), xb3 = ld4(bp1 + 4);
  for (int kt = 0; kt < nk; ++kt) {
    __syncthreads();
    {
      const float v0[8] = {xa0.x, xa0.y, xa0.z, xa0.w, xa1.x, xa1.y, xa1.z, xa1.w};
      const float v1[8] = {xa2.x, xa2.y, xa2.z, xa2.w, xa3.x, xa3.y, xa3.z, xa3.w};
      const float v2[8] = {xb0.x, xb0.y, xb0.z, xb0.w, xb1.x, xb1.y, xb1.z, xb1.w};
      const float v3[8] = {xb2.x, xb2.y, xb2.z, xb2.w, xb3.x, xb3.y, xb3.z, xb3.w};
      *(uint4*)&As[iA0] = pack8(v0);
      *(uint4*)&As[iA1] = pack8(v1);
      *(uint4*)&Bs[iA0] = pack8(v2);
      *(uint4*)&Bs[iA1] = pack8(v3);
    }
    __syncthreads();
    if (kt + 1 < nk) {
      ap0 += 64; ap1 += 64; bp0 += 64; bp1 += 64;
      xa0 = ld4(ap0); xa1 = ld4(ap0 + 4); xa2 = ld4(ap1); xa3 = ld4(ap1 + 4);
      xb0 = ld4(bp0); xb1 = ld4(bp0 + 4); xb2 = ld4(bp1); xb3 = ld4(bp1 + 4);
    }
#pragma unroll
    for (int kc = 0; kc < 2; ++kc) {
      const int c8 = kq8 + 4 * kc;
      bh8 aa0 = lds_rd(As, wm + r0, c8);
      bh8 aa1 = lds_rd(As, wm + 16 + r0, c8);
      bh8 bb0 = lds_rd(Bs, wn + r0, c8);
      bh8 bb1 = lds_rd(Bs, wn + 16 + r0, c8);
      acc00 = __builtin_amdgcn_mfma_f32_16x16x32_bf16(aa0, bb0, acc00, 0, 0, 0);
      acc01 = __builtin_amdgcn_mfma_f32_16x16x32_bf16(aa0, bb1, acc01, 0, 0, 0);
      acc10 = __builtin_amdgcn_mfma_f32_16x16x32_bf16(aa1, bb0, acc10, 0, 0, 0);
      acc11 = __builtin_amdgcn_mfma_f32_16x16x32_bf16(aa1, bb1, acc11, 0, 0, 0);
    }
  }

  fv4 accs[2][2] = {{acc00, acc01}, {acc10, acc11}};
#pragma unroll
  for (int rb = 0; rb < 2; ++rb) {
#pragma unroll
    for (int cbl = 0; cbl < 2; ++cbl) {
#pragma unroll
      for (int j = 0; j < 4; ++j) {
        const int r = bm0 + wm + rb * 16 + (lane >> 4) * 4 + j;
        const int c = bn0 + wn + cbl * 16 + (lane & 15);
        if (r >= a.M) continue;
        const float v = accs[rb][cbl][j];
        if (a.epi == 1) {
          a.Cb[(long)r * a.ldc + c] = f2b(v);
        } else if (a.epi == 2) {
          const float x = tanhf(v + a.e0[c]);
          if (c < 512) a.Cf[(long)r * 512 + c] = x;
          else         a.Cf2[(long)r * 512 + (c - 512)] = x;
        } else {
          a.Cf[(long)r * a.ldc + c] = v + a.e0[c];
        }
      }
    }
  }
}

// ===========================================================================
// Dual batched GEMM 64x64 (verified): EPI 2 = raw K1/K2 store (GK)
// ===========================================================================
struct GA2 {
  const u16* A1; const u16* A2; const u16* B1; const u16* B2;
  long lda, ldb, sAz, sBz;
  float* Cf; float* Cf2;
  long ldc, sCz;
  int M, K;
};

__device__ __forceinline__ void gemm2_core(const GA2& a, u16* As1, u16* As2,
                                           u16* Bs1, u16* Bs2,
                                           int bx, int by, int bz, int t) {
  const int z = bz;
  const int bm0 = bx * 64, bn0 = by * 64;
  const int lane = t & 63, w = t >> 6;
  const int wm = (w >> 1) * 32, wn = (w & 1) * 32;
  const u16* A1b = a.A1 + (long)z * a.sAz;
  const u16* A2b = a.A2 + (long)z * a.sAz;
  const u16* B1b = a.B1 + (long)z * a.sBz;
  const u16* B2b = a.B2 + (long)z * a.sBz;

  const int sr = t >> 3, sc8 = t & 7, sc = sc8 * 8;
  const long aoff0 = (long)(bm0 + sr) * a.lda + sc;
  const long aoff1 = (long)(bm0 + sr + 32) * a.lda + sc;
  const long boff0 = (long)(bn0 + sr) * a.ldb + sc;
  const long boff1 = (long)(bn0 + sr + 32) * a.ldb + sc;
  const u16 *a1p0 = A1b + aoff0, *a1p1 = A1b + aoff1;
  const u16 *a2p0 = A2b + aoff0, *a2p1 = A2b + aoff1;
  const u16 *b1p0 = B1b + boff0, *b1p1 = B1b + boff1;
  const u16 *b2p0 = B2b + boff0, *b2p1 = B2b + boff1;
  const int iA0 = sr * 64 + ((sc8 ^ (sr & 7)) << 3);
  const int iA1 = iA0 + 32 * 64;

  fv4 zero = {0.f, 0.f, 0.f, 0.f};
  fv4 p00 = zero, p01 = zero, p10 = zero, p11 = zero;
  fv4 q00 = zero, q01 = zero, q10 = zero, q11 = zero;
  const int r0 = lane & 15, kq8 = lane >> 4;
  const int nk = a.K >> 6;

  uint4 a1v0 = *(const uint4*)a1p0, a1v1 = *(const uint4*)a1p1;
  uint4 a2v0 = *(const uint4*)a2p0, a2v1 = *(const uint4*)a2p1;
  uint4 b1v0 = *(const uint4*)b1p0, b1v1 = *(const uint4*)b1p1;
  uint4 b2v0 = *(const uint4*)b2p0, b2v1 = *(const uint4*)b2p1;
  for (int kt = 0; kt < nk; ++kt) {
    __syncthreads();
    *(uint4*)&As1[iA0] = a1v0; *(uint4*)&As1[iA1] = a1v1;
    *(uint4*)&As2[iA0] = a2v0; *(uint4*)&As2[iA1] = a2v1;
    *(uint4*)&Bs1[iA0] = b1v0; *(uint4*)&Bs1[iA1] = b1v1;
    *(uint4*)&Bs2[iA0] = b2v0; *(uint4*)&Bs2[iA1] = b2v1;
    __syncthreads();
    if (kt + 1 < nk) {
      a1p0 += 64; a1p1 += 64; a2p0 += 64; a2p1 += 64;
      b1p0 += 64; b1p1 += 64; b2p0 += 64; b2p1 += 64;
      a1v0 = *(const uint4*)a1p0; a1v1 = *(const uint4*)a1p1;
      a2v0 = *(const uint4*)a2p0; a2v1 = *(const uint4*)a2p1;
      b1v0 = *(const uint4*)b1p0; b1v1 = *(const uint4*)b1p1;
      b2v0 = *(const uint4*)b2p0; b2v1 = *(const uint4*)b2p1;
    }
#pragma unroll
    for (int kc = 0; kc < 2; ++kc) {
      const int c8 = kq8 + 4 * kc;
      bh8 x0 = lds_rd(As1, wm + r0, c8);
      bh8 x1 = lds_rd(As1, wm + 16 + r0, c8);
      bh8 y0 = lds_rd(Bs1, wn + r0, c8);
      bh8 y1 = lds_rd(Bs1, wn + 16 + r0, c8);
      p00 = __builtin_amdgcn_mfma_f32_16x16x32_bf16(x0, y0, p00, 0, 0, 0);
      p01 = __builtin_amdgcn_mfma_f32_16x16x32_bf16(x0, y1, p01, 0, 0, 0);
      p10 = __builtin_amdgcn_mfma_f32_16x16x32_bf16(x1, y0, p10, 0, 0, 0);
      p11 = __builtin_amdgcn_mfma_f32_16x16x32_bf16(x1, y1, p11, 0, 0, 0);
      bh8 u0 = lds_rd(As2, wm + r0, c8);
      bh8 u1 = lds_rd(As2, wm + 16 + r0, c8);
      bh8 v0 = lds_rd(Bs2, wn + r0, c8);
      bh8 v1 = lds_rd(Bs2, wn + 16 + r0, c8);
      q00 = __builtin_amdgcn_mfma_f32_16x16x32_bf16(u0, v0, q00, 0, 0, 0);
      q01 = __builtin_amdgcn_mfma_f32_16x16x32_bf16(u0, v1, q01, 0, 0, 0);
      q10 = __builtin_amdgcn_mfma_f32_16x16x32_bf16(u1, v0, q10, 0, 0, 0);
      q11 = __builtin_amdgcn_mfma_f32_16x16x32_bf16(u1, v1, q11, 0, 0, 0);
    }
  }

  fv4 pa[2][2] = {{p00, p01}, {p10, p11}};
  fv4 qa[2][2] = {{q00, q01}, {q10, q11}};
#pragma unroll
  for (int rb = 0; rb < 2; ++rb) {
#pragma unroll
    for (int cbl = 0; cbl < 2; ++cbl) {
#pragma unroll
      for (int j = 0; j < 4; ++j) {
        const int r = bm0 + wm + rb * 16 + (lane >> 4) * 4 + j;
        const int c = bn0 + wn + cbl * 16 + (lane & 15);
        const long idx = (long)z * a.sCz + (long)r * a.ldc + c;
        a.Cf[idx] = pa[rb][cbl][j];
        a.Cf2[idx] = qa[rb][cbl][j];
      }
    }
  }
}

// ===========================================================================
// Elementwise / transpose units (verified)
// ===========================================================================
__device__ __forceinline__ void tpf32_unit(const float* src, long lds, u16* dst, long ldd,
                                           int tr, int tc, int t, float T[64][65]) {
  const int c = t & 63, rg = t >> 6;
#pragma unroll 4
  for (int i = 0; i < 16; ++i) {
    const int r = rg + 4 * i;
    T[r][c] = src[(long)(tr * 64 + r) * lds + tc * 64 + c];
  }
  __syncthreads();
#pragma unroll 4
  for (int i = 0; i < 16; ++i) {
    const int r = rg + 4 * i;
    dst[(long)(tc * 64 + r) * ldd + tr * 64 + c] = f2b(T[c][r]);
  }
}

__device__ __forceinline__ void tpb16_unit(const u16* src, u16* dst, int b, int w32,
                                           int t, float T[64][65]) {
  const int tr = w32 >> 3, tc = w32 & 7;
  const u16* s = src + (long)b * 131072;
  u16* d = dst + (long)b * 131072;
  const int c = t & 63, rg = t >> 6;
#pragma unroll 4
  for (int i = 0; i < 16; ++i) {
    const int r = rg + 4 * i;
    T[r][c] = b2f(s[(long)(tr * 64 + r) * 512 + tc * 64 + c]);
  }
  __syncthreads();
#pragma unroll 4
  for (int i = 0; i < 16; ++i) {
    const int r = rg + 4 * i;
    d[(long)(tc * 64 + r) * 256 + tr * 64 + c] = f2b(T[c][r]);
  }
}

__device__ __forceinline__ void cvt_unit(const float* s, u16* d, long blk, int t) {
  const long idx = blk * 2048 + t * 8;
  const float4 x0 = ld4(s + idx), x1 = ld4(s + idx + 4);
  const float v[8] = {x0.x, x0.y, x0.z, x0.w, x1.x, x1.y, x1.z, x1.w};
  *(uint4*)(d + idx) = pack8(v);
}

__device__ __forceinline__ void ln_unit(const FA& f, int u, int t) {
  const int lane = t & 63, e = lane * 8;
  const int row = u * 4 + (t >> 6);
  const float* p = f.condpre + (long)row * 512 + e;
  const float4 x0 = ld4(p), x1 = ld4(p + 4);
  float v[8] = {x0.x, x0.y, x0.z, x0.w, x1.x, x1.y, x1.z, x1.w};
  float s = 0.f, sq = 0.f;
#pragma unroll
  for (int i = 0; i < 8; ++i) { s += v[i]; sq += v[i] * v[i]; }
#pragma unroll
  for (int m = 1; m < 64; m <<= 1) { s += __shfl_xor(s, m); sq += __shfl_xor(sq, m); }
  const float mu = s * (1.f / 512.f);
  const float iv = rsqrtf(sq * (1.f / 512.f) - mu * mu + LN_EPS);
  const float4 g0 = ld4(f.ln1g + e), g1 = ld4(f.ln1g + e + 4);
  const float4 b0 = ld4(f.ln1b + e), b1 = ld4(f.ln1b + e + 4);
  const float gg[8] = {g0.x, g0.y, g0.z, g0.w, g1.x, g1.y, g1.z, g1.w};
  const float bb[8] = {b0.x, b0.y, b0.z, b0.w, b1.x, b1.y, b1.z, b1.w};
  float o[8], osq[8];
#pragma unroll
  for (int i = 0; i < 8; ++i) {
    o[i] = (v[i] - mu) * iv * gg[i] + bb[i];
    osq[i] = o[i] * o[i];
  }
  *(uint4*)(f.cb_bf + (long)row * 512 + e) = pack8(o);
  *(uint4*)(f.cbsq_bf + (long)row * 512 + e) = pack8(osq);
}

__device__ __forceinline__ void a96_unit(const FA& f, int u, int t) {
  const int lane = t & 63, e = lane * 8;
  const int bl = u * 4 + (t >> 6);
  const int b = bl >> 5, l = bl & 31;
  const float4 ga0 = ld4(f.gam + (long)bl * 512 + e), ga1 = ld4(f.gam + (long)bl * 512 + e + 4);
  const float4 be0 = ld4(f.bet + (long)bl * 512 + e), be1 = ld4(f.bet + (long)bl * 512 + e + 4);
  const float gv[8] = {ga0.x, ga0.y, ga0.z, ga0.w, ga1.x, ga1.y, ga1.z, ga1.w};
  const float bv[8] = {be0.x, be0.y, be0.z, be0.w, be1.x, be1.y, be1.z, be1.w};
  float gg[8], gb[8]; float s1 = 0.f, s2 = 0.f;
#pragma unroll
  for (int i = 0; i < 8; ++i) {
    gg[i] = gv[i] * gv[i]; gb[i] = gv[i] * bv[i];
    s1 += bv[i]; s2 += bv[i] * bv[i];
  }
  const long basei = ((long)b * 96 + l) * 512 + e;
  *(uint4*)(f.A96_bf + basei) = pack8(gv);
  *(uint4*)(f.A96_bf + basei + 32 * 512) = pack8(gb);
  *(uint4*)(f.A96_bf + basei + 64 * 512) = pack8(gg);
#pragma unroll
  for (int m = 1; m < 64; m <<= 1) { s1 += __shfl_xor(s1, m); s2 += __shfl_xor(s2, m); }
  if (lane == 0) { f.sum_be[bl] = s1; f.sum_be2[bl] = s2; }
}

__device__ __forceinline__ void csum_unit(const FA& f, int u, int t) {
  const int lane = t & 63, e = lane * 8;
  const int lh = u * 4 + (t >> 6);
  const int bl = lh >> 3;
  const uint4 up = *(const uint4*)(f.u_bf + (long)lh * 512 + e);
  const u16* us = (const u16*)&up;
  const float4 be0 = ld4(f.bet + (long)bl * 512 + e), be1 = ld4(f.bet + (long)bl * 512 + e + 4);
  const float4 G0 = ld4(f.ln2g + e), G1 = ld4(f.ln2g + e + 4);
  const float4 B0 = ld4(f.ln2b + e), B1 = ld4(f.ln2b + e + 4);
  const float bv[8] = {be0.x, be0.y, be0.z, be0.w, be1.x, be1.y, be1.z, be1.w};
  const float Gv[8] = {G0.x, G0.y, G0.z, G0.w, G1.x, G1.y, G1.z, G1.w};
  const float Bv[8] = {B0.x, B0.y, B0.z, B0.w, B1.x, B1.y, B1.z, B1.w};
  float a2 = 0.f, a3 = 0.f, a4 = 0.f;
#pragma unroll
  for (int i = 0; i < 8; ++i) {
    const float uu = b2f(us[i]);
    const float t1 = Gv[i] * uu;
    a2 += bv[i] * t1; a3 += t1; a4 += Bv[i] * uu;
  }
#pragma unroll
  for (int m = 1; m < 64; m <<= 1) {
    a2 += __shfl_xor(a2, m); a3 += __shfl_xor(a3, m); a4 += __shfl_xor(a4, m);
  }
  if (lane == 0) { f.c2[lh] = a2; f.c3[lh] = a3; f.c4[lh] = a4; }
}

// ===========================================================================
// Phase kernels (6 dispatches)
// ===========================================================================
// A: G2-f32(512) + G1a(128) + G1b(64) + k cvt(1024) + Wv(128) + Wfc(128)
//    + WkT(64) + kT(512) = 2560
__global__ __launch_bounds__(256) void pA_k(FA f) {
  __shared__ __align__(16) char smem[16704];
  u16* As = (u16*)smem;
  u16* Bs = (u16*)(smem + 8192);
  float (*T)[65] = (float(*)[65])smem;
  const int u = blockIdx.x, t = threadIdx.x;
  if (u < 512) {
    GAF a = {}; a.Af = f.k; a.Bf = f.Wvp; a.lda = 512; a.ldb = 512;
    a.Cf = f.condpre; a.ldc = 512; a.M = 4096; a.K = 512; a.epi = 4; a.e0 = f.bvp;
    gemm_core_f32(a, As, Bs, u % 64, u / 64, t);
  } else if (u < 640) {
    const int r = u - 512;
    GAF a = {}; a.Af = f.q; a.Bf = f.Wg; a.lda = 512; a.ldb = 512;
    a.Cf = f.gam; a.Cf2 = f.bet; a.ldc = 512; a.M = 512; a.K = 512; a.epi = 2; a.e0 = f.bg;
    gemm_core_f32(a, As, Bs, r % 8, r / 8, t);
  } else if (u < 704) {
    const int r = u - 640;
    GAF a = {}; a.Af = f.q; a.Bf = f.Wq; a.lda = 512; a.ldb = 512;
    a.Cb = f.qh_bf; a.ldc = 512; a.M = 512; a.K = 512; a.epi = 1;
    gemm_core_f32(a, As, Bs, r % 8, r / 8, t);
  } else if (u < 1728) {
    cvt_unit(f.k, f.k_bf, u - 704, t);
  } else if (u < 1856) {
    cvt_unit(f.Wv, f.Wv_bf, u - 1728, t);
  } else if (u < 1984) {
    cvt_unit(f.Wfc, f.Wfc_bf, u - 1856, t);
  } else if (u < 2048) {
    const int tt = u - 1984;
    tpf32_unit(f.Wk, 512, f.WkT_bf, 512, tt >> 3, tt & 7, t, T);
  } else {
    const int tt = u - 2048;
    const int b = tt >> 5, w32 = tt & 31;
    tpf32_unit(f.k + (long)b * 131072, 512, f.kT_bf + (long)b * 131072, 256,
               w32 >> 3, w32 & 7, t, T);
  }
}

// B: LN(1024) + A96(128) + Gu·w1(512) = 1664
__global__ __launch_bounds__(256) void pB_k(FA f) {
  __shared__ __align__(16) char smem[16384];
  u16* As = (u16*)smem;
  u16* Bs = (u16*)(smem + 8192);
  const int u = blockIdx.x, t = threadIdx.x;
  if (u < 1024) {
    ln_unit(f, u, t);
  } else if (u < 1152) {
    a96_unit(f, u - 1024, t);
  } else {
    const int r = u - 1152;
    GA a = {}; a.A = f.qh_bf; a.lda = 512; a.sAz = 64;
    a.B = f.WkT_bf; a.ldb = 512; a.sBz = 64;
    a.Cb = f.u_bf; a.Cb2 = f.w1_bf; a.ldc = 512; a.M = 512; a.K = 64; a.epi = 6;
    a.e0 = f.gam; a.e1 = f.ln2g;
    gemm_core(a, As, Bs, r % 8, (r / 8) % 8, r / 64, t);
  }
}

// C: GP(128) + cbT(512) + csum(1024) + GK-raw(256) = 1920
__global__ __launch_bounds__(256) void pC_k(FA f) {
  __shared__ __align__(16) char smem[32768];
  const int u = blockIdx.x, t = threadIdx.x;
  if (u < 128) {
    u16* As = (u16*)smem; u16* Bs = (u16*)(smem + 8192);
    GA a = {}; a.A = f.A96_bf; a.lda = 512; a.sAz = 96 * 512;
    a.B = f.cb_bf; a.Balt = f.cbsq_bf; a.ldb = 512; a.sBz = 256 * 512;
    a.Cf = f.P; a.ldc = 256; a.sCz = 96 * 256; a.M = 96; a.K = 512; a.epi = 0;
    gemm_core(a, As, Bs, u % 2, (u / 2) % 4, u / 8, t);
  } else if (u < 640) {
    float (*T)[65] = (float(*)[65])smem;
    const int tt = u - 128;
    tpb16_unit(f.cb_bf, f.cbT_bf, tt >> 5, tt & 31, t, T);
  } else if (u < 1664) {
    csum_unit(f, u - 640, t);
  } else {
    const int r = u - 1664;
    u16* As1 = (u16*)smem; u16* As2 = (u16*)(smem + 8192);
    u16* Bs1 = (u16*)(smem + 16384); u16* Bs2 = (u16*)(smem + 24576);
    GA2 d = {};
    d.A1 = f.u_bf; d.A2 = f.w1_bf; d.B1 = f.k_bf; d.B2 = f.cb_bf;
    d.lda = 512; d.ldb = 512; d.sAz = 256 * 512; d.sBz = 256 * 512;
    d.Cf = f.K1; d.Cf2 = f.K2; d.ldc = 256; d.sCz = 256 * 256; d.M = 256; d.K = 512;
    gemm2_core(d, As1, As2, Bs1, Bs2, r % 4, (r / 4) % 4, r / 16, t);
  }
}

// E: fused softmax + GT (512 blocks: bx 4, by 8, z 16)
__global__ __launch_bounds__(256) void pE_k(FA f) {
  __shared__ __align__(16) u16 w_lds[4 * 64 * 64];   // 32 KB: [kt][row][swz col]
  __shared__ float iv_lds[8][256];                   // 8 KB
  __shared__ float s1_lds[64], s2_lds[64];
  __shared__ __align__(16) u16 Bs1[64 * 64];         // 8 KB
  __shared__ __align__(16) u16 Bs2[64 * 64];         // 8 KB

  const int u = blockIdx.x, t = threadIdx.x;
  const int bx = u & 3, by = (u >> 2) & 7, z = u >> 5;
  const int bm0 = bx * 64, bn0 = by * 64;

  // ---------- softmax prologue: 64 rows x 256 k; thread = (row=t>>2, q=t&3) ----------
  {
    const int row = t >> 2, qq = t & 3;
    const int r = bm0 + row;
    const int lh = z * 256 + r;
    const int bl = z * 32 + (r >> 3);
    const int l = (r >> 3) & 31;
    const float* k1p = f.K1 + (long)lh * 256 + qq * 64;
    const float* k2p = f.K2 + (long)lh * 256 + qq * 64;
    const float* Pb  = f.P + ((long)z * 96 + l) * 256 + qq * 64;
    const float sbe = f.sum_be[bl], sbe2 = f.sum_be2[bl];
    const float C2 = f.c2[lh], C3 = f.c3[lh], C4 = f.c4[lh];

    // pass 1: row max
    float mx = -3.4e38f;
    for (int j = 0; j < 64; j += 4) {
      const float4 k1 = ld4(k1p + j), k2 = ld4(k2p + j);
      const float4 p0 = ld4(Pb + j), pgb = ld4(Pb + 8192 + j), pg2 = ld4(Pb + 16384 + j);
      const float k1s[4] = {k1.x, k1.y, k1.z, k1.w};
      const float k2s[4] = {k2.x, k2.y, k2.z, k2.w};
      const float p0s[4] = {p0.x, p0.y, p0.z, p0.w};
      const float pgbs[4] = {pgb.x, pgb.y, pgb.z, pgb.w};
      const float pg2s[4] = {pg2.x, pg2.y, pg2.z, pg2.w};
#pragma unroll
      for (int i = 0; i < 4; ++i) {
        const float mu = (p0s[i] + sbe) * (1.f / 512.f);
        const float msq = (pg2s[i] + 2.f * pgbs[i] + sbe2) * (1.f / 512.f);
        const float iv = rsqrtf(msq - mu * mu + LN_EPS);
        const float lg = k1s[i] + C4 + iv * (k2s[i] + C2 - mu * C3);
        mx = fmaxf(mx, lg);
      }
    }
    mx = fmaxf(mx, __shfl_xor(mx, 1));
    mx = fmaxf(mx, __shfl_xor(mx, 2));

    // pass 2: exp, store ex (bf16) + iv; accumulate sums
    float zs = 0.f, a1 = 0.f, a2 = 0.f;
    const int rsw = row & 7;
    for (int j8 = 0; j8 < 64; j8 += 8) {
      float exv[8], ivv[8];
#pragma unroll
      for (int h4 = 0; h4 < 2; ++h4) {
        const int j = j8 + h4 * 4;
        const float4 k1 = ld4(k1p + j), k2 = ld4(k2p + j);
        const float4 p0 = ld4(Pb + j), pgb = ld4(Pb + 8192 + j), pg2 = ld4(Pb + 16384 + j);
        const float k1s[4] = {k1.x, k1.y, k1.z, k1.w};
        const float k2s[4] = {k2.x, k2.y, k2.z, k2.w};
        const float p0s[4] = {p0.x, p0.y, p0.z, p0.w};
        const float pgbs[4] = {pgb.x, pgb.y, pgb.z, pgb.w};
        const float pg2s[4] = {pg2.x, pg2.y, pg2.z, pg2.w};
#pragma unroll
        for (int i = 0; i < 4; ++i) {
          const float mu = (p0s[i] + sbe) * (1.f / 512.f);
          const float msq = (pg2s[i] + 2.f * pgbs[i] + sbe2) * (1.f / 512.f);
          const float iv = rsqrtf(msq - mu * mu + LN_EPS);
          const float lg = k1s[i] + C4 + iv * (k2s[i] + C2 - mu * C3);
          const float ex = expf(lg - mx);
          zs += ex;
          a1 += ex * iv;
          a2 += ex * iv * mu;
          exv[h4 * 4 + i] = ex;
          ivv[h4 * 4 + i] = iv;
        }
      }
      *(uint4*)&w_lds[qq * 4096 + row * 64 + (((j8 >> 3) ^ rsw) << 3)] = pack8(exv);
      if ((row & 7) == 0) {
        *(float4*)&iv_lds[row >> 3][qq * 64 + j8] = make_float4(ivv[0], ivv[1], ivv[2], ivv[3]);
        *(float4*)&iv_lds[row >> 3][qq * 64 + j8 + 4] = make_float4(ivv[4], ivv[5], ivv[6], ivv[7]);
      }
    }
    zs += __shfl_xor(zs, 1); zs += __shfl_xor(zs, 2);
    a1 += __shfl_xor(a1, 1); a1 += __shfl_xor(a1, 2);
    a2 += __shfl_xor(a2, 1); a2 += __shfl_xor(a2, 2);
    const float rz = 1.f / zs;
    if (qq == 0) { s1_lds[row] = a1 * rz; s2_lds[row] = a2 * rz; }

    // pass 3: rescale this thread's stored ex by rz in-place -> w (bf16)
    for (int j8 = 0; j8 < 64; j8 += 8) {
      u16* slot = &w_lds[qq * 4096 + row * 64 + (((j8 >> 3) ^ rsw) << 3)];
      uint4 pk = *(uint4*)slot;
      const u16* pe = (const u16*)&pk;
      float sv[8];
#pragma unroll
      for (int e = 0; e < 8; ++e) sv[e] = b2f(pe[e]) * rz;
      *(uint4*)slot = pack8(sv);
    }
  }

  // ---------- GT dual GEMM: T1 = w @ kT^T, T2 = (w*iv) @ cbT^T ----------
  const int lane = t & 63, w = t >> 6;
  const int wm = (w >> 1) * 32, wn = (w & 1) * 32;
  const u16* B1b = f.kT_bf + (long)z * (512 * 256);
  const u16* B2b = f.cbT_bf + (long)z * (512 * 256);
  const int srb = t >> 3, sc8 = t & 7, sc = sc8 * 8;
  const int iB0 = srb * 64 + ((sc8 ^ (srb & 7)) << 3);
  const int iB1 = iB0 + 32 * 64;
  const u16* b1p0 = B1b + (long)(bn0 + srb) * 256 + sc;
  const u16* b1p1 = B1b + (long)(bn0 + srb + 32) * 256 + sc;
  const u16* b2p0 = B2b + (long)(bn0 + srb) * 256 + sc;
  const u16* b2p1 = B2b + (long)(bn0 + srb + 32) * 256 + sc;

  fv4 zero = {0.f, 0.f, 0.f, 0.f};
  fv4 p00 = zero, p01 = zero, p10 = zero, p11 = zero;
  fv4 q00 = zero, q01 = zero, q10 = zero, q11 = zero;
  const int r0 = lane & 15, kq8 = lane >> 4;
  const int rowA0 = wm + r0, rowA1 = wm + 16 + r0;
  const float* ivA0 = &iv_lds[rowA0 >> 3][0];
  const float* ivA1 = &iv_lds[rowA1 >> 3][0];

  uint4 b1v0 = *(const uint4*)b1p0, b1v1 = *(const uint4*)b1p1;
  uint4 b2v0 = *(const uint4*)b2p0, b2v1 = *(const uint4*)b2p1;
  for (int kt = 0; kt < 4; ++kt) {
    __syncthreads();
    *(uint4*)&Bs1[iB0] = b1v0; *(uint4*)&Bs1[iB1] = b1v1;
    *(uint4*)&Bs2[iB0] = b2v0; *(uint4*)&Bs2[iB1] = b2v1;
    __syncthreads();
    if (kt + 1 < 4) {
      b1p0 += 64; b1p1 += 64; b2p0 += 64; b2p1 += 64;
      b1v0 = *(const uint4*)b1p0; b1v1 = *(const uint4*)b1p1;
      b2v0 = *(const uint4*)b2p0; b2v1 = *(const uint4*)b2p1;
    }
    const u16* wp = &w_lds[kt * 4096];
#pragma unroll
    for (int kc = 0; kc < 2; ++kc) {
      const int c8 = kq8 + 4 * kc;
      const int ko = kt * 64 + c8 * 8;
      // A1 fragments: direct reads of w
      bh8 x0 = lds_rd(wp, rowA0, c8);
      bh8 x1 = lds_rd(wp, rowA1, c8);
      bh8 y0 = lds_rd(Bs1, wn + r0, c8);
      bh8 y1 = lds_rd(Bs1, wn + 16 + r0, c8);
      p00 = __builtin_amdgcn_mfma_f32_16x16x32_bf16(x0, y0, p00, 0, 0, 0);
      p01 = __builtin_amdgcn_mfma_f32_16x16x32_bf16(x0, y1, p01, 0, 0, 0);
      p10 = __builtin_amdgcn_mfma_f32_16x16x32_bf16(x1, y0, p10, 0, 0, 0);
      p11 = __builtin_amdgcn_mfma_f32_16x16x32_bf16(x1, y1, p11, 0, 0, 0);
      // A2 fragments: w * iv on the fly
      const float4 i00 = ld4(ivA0 + ko), i01 = ld4(ivA0 + ko + 4);
      const float4 i10 = ld4(ivA1 + ko), i11 = ld4(ivA1 + ko + 4);
      const float iv0[8] = {i00.x, i00.y, i00.z, i00.w, i01.x, i01.y, i01.z, i01.w};
      const float iv1[8] = {i10.x, i10.y, i10.z, i10.w, i11.x, i11.y, i11.z, i11.w};
      const u16* x0p = (const u16*)&x0;
      const u16* x1p = (const u16*)&x1;
      float w0[8], w1v[8];
#pragma unroll
      for (int e = 0; e < 8; ++e) {
        w0[e] = b2f(x0p[e]) * iv0[e];
        w1v[e] = b2f(x1p[e]) * iv1[e];
      }
      uint4 u0u = pack8(w0); bh8 u0 = *(bh8*)&u0u;
      uint4 u1u = pack8(w1v); bh8 u1 = *(bh8*)&u1u;
      bh8 v0 = lds_rd(Bs2, wn + r0, c8);
      bh8 v1 = lds_rd(Bs2, wn + 16 + r0, c8);
      q00 = __builtin_amdgcn_mfma_f32_16x16x32_bf16(u0, v0, q00, 0, 0, 0);
      q01 = __builtin_amdgcn_mfma_f32_16x16x32_bf16(u0, v1, q01, 0, 0, 0);
      q10 = __builtin_amdgcn_mfma_f32_16x16x32_bf16(u1, v0, q10, 0, 0, 0);
      q11 = __builtin_amdgcn_mfma_f32_16x16x32_bf16(u1, v1, q11, 0, 0, 0);
    }
  }

  // epilogue: s = T1 + B2 + G2*(g*T2 + be*S1 - S2)
  fv4 pa[2][2] = {{p00, p01}, {p10, p11}};
  fv4 qa[2][2] = {{q00, q01}, {q10, q11}};
#pragma unroll
  for (int rb = 0; rb < 2; ++rb) {
#pragma unroll
    for (int cbl = 0; cbl < 2; ++cbl) {
#pragma unroll
      for (int j = 0; j < 4; ++j) {
        const int rl = wm + rb * 16 + (lane >> 4) * 4 + j;   // local row
        const int rg = bm0 + rl;                              // row in [0,256)
        const int c = bn0 + wn + cbl * 16 + (lane & 15);
        const int lh = z * 256 + rg;
        const int bl = z * 32 + (rg >> 3);
        const float G2d = f.ln2g[c], B2d = f.ln2b[c];
        const float gv = f.gam[(long)bl * 512 + c];
        const float bev = f.bet[(long)bl * 512 + c];
        const float sv = pa[rb][cbl][j] + B2d +
                         G2d * (gv * qa[rb][cbl][j] + bev * s1_lds[rl] - s2_lds[rl]);
        f.s_bf[(long)z * (256 * 512) + (long)rg * 512 + c] = f2b(sv);
        (void)lh;
      }
    }
  }
}

// F: attn = s_h @ Wv_h^T (64)
__global__ __launch_bounds__(256) void pF_k(FA f) {
  __shared__ __align__(16) char smem[16384];
  u16* As = (u16*)smem; u16* Bs = (u16*)(smem + 8192);
  const int u = blockIdx.x, t = threadIdx.x;
  GA a = {}; a.A = f.s_bf; a.lda = 4096; a.sAz = 512;
  a.B = f.Wv_bf; a.ldb = 512; a.sBz = 64 * 512;
  a.Cb = f.attn_bf; a.ldc = 512; a.sCz = 64; a.M = 512; a.K = 512; a.epi = 1;
  gemm_core(a, As, Bs, u % 8, 0, u / 8, t);
}

// G: out = attn @ Wfc^T (64)
__global__ __launch_bounds__(256) void pG_k(FA f) {
  __shared__ __align__(16) char smem[16384];
  u16* As = (u16*)smem; u16* Bs = (u16*)(smem + 8192);
  const int u = blockIdx.x, t = threadIdx.x;
  GA a = {}; a.A = f.attn_bf; a.lda = 512;
  a.B = f.Wfc_bf; a.ldb = 512;
  a.Cf = f.out; a.ldc = 512; a.M = 512; a.K = 512; a.epi = 0;
  gemm_core(a, As, Bs, u % 8, u / 8, 0, t);
}

}  // namespace

extern "C" void kernel_launch(void* const* d_in, const int* in_sizes, int n_in,
                              void* d_out, int out_size, void* d_ws, size_t ws_size,
                              hipStream_t stream) {
  (void)in_sizes; (void)n_in; (void)out_size;
  FA fa;
  fa.q    = (const float*)d_in[0];
  fa.k    = (const float*)d_in[1];
  fa.Wq   = (const float*)d_in[3];
  fa.Wk   = (const float*)d_in[4];
  fa.Wv   = (const float*)d_in[5];
  fa.Wfc  = (const float*)d_in[6];
  fa.Wg   = (const float*)d_in[7];
  fa.bg   = (const float*)d_in[8];
  fa.Wvp  = (const float*)d_in[9];
  fa.bvp  = (const float*)d_in[10];
  fa.ln1g = (const float*)d_in[11];
  fa.ln1b = (const float*)d_in[12];
  fa.ln2g = (const float*)d_in[13];
  fa.ln2b = (const float*)d_in[14];
  fa.out  = (float*)d_out;

  char* base = (char*)d_ws;
  size_t off = 0;
  auto au16 = [&](size_t n) -> u16* {
    u16* p = (u16*)(base + off); off = (off + n * 2 + 255) & ~(size_t)255; return p;
  };
  auto af32 = [&](size_t n) -> float* {
    float* p = (float*)(base + off); off = (off + n * 4 + 255) & ~(size_t)255; return p;
  };
  (void)au16(262144);               // layout parity (unused)
  (void)au16(524288);
  (void)au16(262144);
  (void)au16(262144);
  fa.WkT_bf  = au16(262144);
  fa.Wv_bf   = au16(262144);
  fa.Wfc_bf  = au16(262144);
  fa.k_bf    = au16(2097152);
  fa.kT_bf   = au16(2097152);
  fa.qh_bf   = au16(262144);
  fa.gam     = af32(262144);
  fa.bet     = af32(262144);
  fa.condpre = af32(2097152);       // K1 = first half, K2 = second half (post-LN)
  fa.cb_bf   = au16(2097152);
  fa.cbT_bf  = au16(2097152);
  fa.u_bf    = au16(2097152);
  fa.w1_bf   = au16(2097152);
  fa.c2      = af32(4096);
  fa.c3      = af32(4096);
  fa.c4      = af32(4096);
  fa.A96_bf  = au16(16 * 96 * 512);
  fa.sum_be  = af32(512);
  fa.sum_be2 = af32(512);
  fa.P       = af32(16 * 96 * 256);
  float* sbuf   = af32(1048576);
  float* logits = af32(1048576);    // holds cb^2 (bf16) from LN
  (void)au16(1048576);              // w_bf slot (unused now)
  (void)au16(1048576);              // W1_bf slot (unused now)
  (void)af32(4096);                 // S1 (unused)
  (void)af32(4096);                 // S2 (unused)
  fa.attn_bf = au16(262144);
  const size_t need = off;
  fa.s_bf    = (u16*)sbuf;
  fa.cbsq_bf = (u16*)logits;
  fa.K1      = fa.condpre;          // condpre dead after LN (phase B)
  fa.K2      = fa.condpre + 1048576;

  if (ws_size < need) return;

  const dim3 blk(256);
  pA_k<<<dim3(2560), blk, 0, stream>>>(fa);
  pB_k<<<dim3(1664), blk, 0, stream>>>(fa);
  pC_k<<<dim3(1920), blk, 0, stream>>>(fa);
  pE_k<<<dim3(512),  blk, 0, stream>>>(fa);
  pF_k<<<dim3(64),   blk, 0, stream>>>(fa);
  pG_k<<<dim3(64),   blk, 0, stream>>>(fa);
}

// Round 10
// 76.785 us; speedup vs baseline: 1.5818x; 1.4609x over previous
//
#include <hip/hip_runtime.h>
#include <math.h>

namespace {
constexpr float LN_EPS = 1e-5f;

typedef unsigned short u16;
typedef __attribute__((ext_vector_type(8))) short bh8;
typedef __attribute__((ext_vector_type(4))) float fv4;

__device__ __forceinline__ float4 ld4(const float* p) { return *reinterpret_cast<const float4*>(p); }

__device__ __forceinline__ float b2f(u16 x) {
  union { float f; unsigned u; } c; c.u = ((unsigned)x) << 16; return c.f;
}
__device__ __forceinline__ u16 f2b(float f) {  // RTN-even
  union { float f; unsigned u; } c; c.f = f;
  unsigned u = c.u;
  u += 0x7FFFu + ((u >> 16) & 1u);
  return (u16)(u >> 16);
}
__device__ __forceinline__ unsigned pk2(float a, float b) {
  return (unsigned)f2b(a) | ((unsigned)f2b(b) << 16);
}
__device__ __forceinline__ uint4 pack8(const float* v) {
  uint4 r; r.x = pk2(v[0], v[1]); r.y = pk2(v[2], v[3]); r.z = pk2(v[4], v[5]); r.w = pk2(v[6], v[7]);
  return r;
}

// XOR-swizzled LDS tile access: [R][64] u16, 16B slots, c8 ^= row&7
__device__ __forceinline__ bh8 lds_rd(const u16* S, int row, int c8) {
  return *(const bh8*)&S[row * 64 + ((c8 ^ (row & 7)) << 3)];
}

// async global->LDS, 16B per lane; LDS dest = wave-uniform base + lane*16B.
// Swizzle achieved by pre-swizzling the per-lane GLOBAL column (m173 pattern).
__device__ __forceinline__ void gll16(const u16* g, u16* l) {
  __builtin_amdgcn_global_load_lds((const __attribute__((address_space(1))) void*)g,
                                   (__attribute__((address_space(3))) void*)l, 16, 0, 0);
}

struct FA {
  const float *q, *k, *Wq, *Wk, *Wv, *Wfc, *Wg, *bg, *Wvp, *bvp;
  const float *ln1g, *ln1b, *ln2g, *ln2b;
  float* out;
  u16 *WkT_bf, *Wv_bf, *Wfc_bf, *k_bf, *kT_bf, *qh_bf;
  float *gam, *bet, *condpre;
  u16 *cb_bf, *cbT_bf, *u_bf, *w1_bf;
  float *c2, *c3, *c4;
  u16* A96_bf;
  float *sum_be, *sum_be2, *P;
  u16* s_bf;
  u16 *cbsq_bf, *w_bf, *W1_bf;
  float *S1, *S2;
  u16* attn_bf;
  float *K1, *K2;
};

// ===========================================================================
// bf16 GEMM core 64x64, global_load_lds staging. epi: 0 f32, 1 bf16,
// 5 u-remap, 6 u-remap + fused w1
// ===========================================================================
struct GA {
  const u16* A; const u16* B; const u16* Balt;
  long lda, ldb, sAz, sBz;
  float* Cf; u16* Cb; u16* Cb2;
  long ldc, sCz;
  int M, K, epi;
  const float* e0; const float* e1;
};

__device__ __forceinline__ void gemm_core(const GA& a, u16* As, u16* Bs,
                                          int bx, int by, int bz, int t) {
  const int z = bz;
  const int bm0 = bx * 64, bn0 = by * 64;
  const int lane = t & 63, w = t >> 6;
  const int wm = (w >> 1) * 32, wn = (w & 1) * 32;
  const u16* Ab = a.A + (long)z * a.sAz;
  const u16* Bbase = (a.Balt != nullptr && bm0 >= 64) ? a.Balt : a.B;
  const u16* Bb = Bbase + (long)z * a.sBz;

  const int sr = t >> 3;                        // LDS row-in-block 0..31
  const int swc = ((t & 7) ^ (sr & 7)) << 3;    // pre-swizzled source col (elems)
  int ar0 = bm0 + sr;      if (ar0 > a.M - 1) ar0 = a.M - 1;
  int ar1 = bm0 + sr + 32; if (ar1 > a.M - 1) ar1 = a.M - 1;
  const u16* ap0 = Ab + (long)ar0 * a.lda + swc;
  const u16* ap1 = Ab + (long)ar1 * a.lda + swc;
  const u16* bp0 = Bb + (long)(bn0 + sr) * a.ldb + swc;
  const u16* bp1 = Bb + (long)(bn0 + sr + 32) * a.ldb + swc;
  u16* lA0 = As + w * 512;           // wave-uniform LDS bases (linear dest)
  u16* lA1 = As + 2048 + w * 512;
  u16* lB0 = Bs + w * 512;
  u16* lB1 = Bs + 2048 + w * 512;

  fv4 zero = {0.f, 0.f, 0.f, 0.f};
  fv4 acc00 = zero, acc01 = zero, acc10 = zero, acc11 = zero;
  const int r0 = lane & 15, kq8 = lane >> 4;
  const int nk = a.K >> 6;

  for (int kt = 0; kt < nk; ++kt) {
    __syncthreads();
    gll16(ap0, lA0); gll16(ap1, lA1);
    gll16(bp0, lB0); gll16(bp1, lB1);
    __syncthreads();   // compiler drains vmcnt before barrier -> LDS ready
    ap0 += 64; ap1 += 64; bp0 += 64; bp1 += 64;
#pragma unroll
    for (int kc = 0; kc < 2; ++kc) {
      const int c8 = kq8 + 4 * kc;
      bh8 aa0 = lds_rd(As, wm + r0, c8);
      bh8 aa1 = lds_rd(As, wm + 16 + r0, c8);
      bh8 bb0 = lds_rd(Bs, wn + r0, c8);
      bh8 bb1 = lds_rd(Bs, wn + 16 + r0, c8);
      acc00 = __builtin_amdgcn_mfma_f32_16x16x32_bf16(aa0, bb0, acc00, 0, 0, 0);
      acc01 = __builtin_amdgcn_mfma_f32_16x16x32_bf16(aa0, bb1, acc01, 0, 0, 0);
      acc10 = __builtin_amdgcn_mfma_f32_16x16x32_bf16(aa1, bb0, acc10, 0, 0, 0);
      acc11 = __builtin_amdgcn_mfma_f32_16x16x32_bf16(aa1, bb1, acc11, 0, 0, 0);
    }
  }

  fv4 accs[2][2] = {{acc00, acc01}, {acc10, acc11}};
#pragma unroll
  for (int rb = 0; rb < 2; ++rb) {
#pragma unroll
    for (int cbl = 0; cbl < 2; ++cbl) {
#pragma unroll
      for (int j = 0; j < 4; ++j) {
        const int r = bm0 + wm + rb * 16 + (lane >> 4) * 4 + j;
        const int c = bn0 + wn + cbl * 16 + (lane & 15);
        if (r >= a.M) continue;
        const float v = accs[rb][cbl][j];
        if (a.epi == 0) {
          a.Cf[(long)z * a.sCz + (long)r * a.ldc + c] = v;
        } else if (a.epi == 1) {
          a.Cb[(long)z * a.sCz + (long)r * a.ldc + c] = f2b(v);
        } else if (a.epi == 5) {
          a.Cb[((long)r * 8 + z) * a.ldc + c] = f2b(v * 0.125f);
        } else {  // 6: u remap + fused w1
          const u16 ub = f2b(v * 0.125f);
          const long orow = (long)r * 8 + z;
          a.Cb[orow * 512 + c] = ub;
          const float uu = b2f(ub);
          const float t1 = a.e1[c] * uu;
          a.Cb2[orow * 512 + c] = f2b(a.e0[(long)r * 512 + c] * t1);
        }
      }
    }
  }
}

// ===========================================================================
// f32-staging GEMM core 64x64 (verified; unchanged — conversion in staging).
// epi: 1 bf16, 2 film, 4 +bias
// ===========================================================================
struct GAF {
  const float* Af; const float* Bf;
  long lda, ldb;
  float* Cf; u16* Cb; float* Cf2;
  long ldc;
  int M, K, epi;
  const float* e0;
};

__device__ __forceinline__ void gemm_core_f32(const GAF& a, u16* As, u16* Bs,
                                              int bx, int by, int t) {
  const int bm0 = bx * 64, bn0 = by * 64;
  const int lane = t & 63, w = t >> 6;
  const int wm = (w >> 1) * 32, wn = (w & 1) * 32;
  const int sr = t >> 3, sc8 = t & 7, sc = sc8 * 8;
  int ar0 = bm0 + sr;      if (ar0 > a.M - 1) ar0 = a.M - 1;
  int ar1 = bm0 + sr + 32; if (ar1 > a.M - 1) ar1 = a.M - 1;
  const float* ap0 = a.Af + (long)ar0 * a.lda + sc;
  const float* ap1 = a.Af + (long)ar1 * a.lda + sc;
  const float* bp0 = a.Bf + (long)(bn0 + sr) * a.ldb + sc;
  const float* bp1 = a.Bf + (long)(bn0 + sr + 32) * a.ldb + sc;
  const int iA0 = sr * 64 + ((sc8 ^ (sr & 7)) << 3);
  const int iA1 = iA0 + 32 * 64;

  fv4 zero = {0.f, 0.f, 0.f, 0.f};
  fv4 acc00 = zero, acc01 = zero, acc10 = zero, acc11 = zero;
  const int r0 = lane & 15, kq8 = lane >> 4;
  const int nk = a.K >> 6;

  float4 xa0 = ld4(ap0), xa1 = ld4(ap0 + 4), xa2 = ld4(ap1), xa3 = ld4(ap1 + 4);
  float4 xb0 = ld4(bp0), xb1 = ld4(bp0 + 4), xb2 = ld4(bp1), xb3 = ld4(bp1 + 4);
  for (int kt = 0; kt < nk; ++kt) {
    __syncthreads();
    {
      const float v0[8] = {xa0.x, xa0.y, xa0.z, xa0.w, xa1.x, xa1.y, xa1.z, xa1.w};
      const float v1[8] = {xa2.x, xa2.y, xa2.z, xa2.w, xa3.x, xa3.y, xa3.z, xa3.w};
      const float v2[8] = {xb0.x, xb0.y, xb0.z, xb0.w, xb1.x, xb1.y, xb1.z, xb1.w};
      const float v3[8] = {xb2.x, xb2.y, xb2.z, xb2.w, xb3.x, xb3.y, xb3.z, xb3.w};
      *(uint4*)&As[iA0] = pack8(v0);
      *(uint4*)&As[iA1] = pack8(v1);
      *(uint4*)&Bs[iA0] = pack8(v2);
      *(uint4*)&Bs[iA1] = pack8(v3);
    }
    __syncthreads();
    if (kt + 1 < nk) {
      ap0 += 64; ap1 += 64; bp0 += 64; bp1 += 64;
      xa0 = ld4(ap0); xa1 = ld4(ap0 + 4); xa2 = ld4(ap1); xa3 = ld4(ap1 + 4);
      xb0 = ld4(bp0); xb1 = ld4(bp0 + 4); xb2 = ld4(bp1); xb3 = ld4(bp1 + 4);
    }
#pragma unroll
    for (int kc = 0; kc < 2; ++kc) {
      const int c8 = kq8 + 4 * kc;
      bh8 aa0 = lds_rd(As, wm + r0, c8);
      bh8 aa1 = lds_rd(As, wm + 16 + r0, c8);
      bh8 bb0 = lds_rd(Bs, wn + r0, c8);
      bh8 bb1 = lds_rd(Bs, wn + 16 + r0, c8);
      acc00 = __builtin_amdgcn_mfma_f32_16x16x32_bf16(aa0, bb0, acc00, 0, 0, 0);
      acc01 = __builtin_amdgcn_mfma_f32_16x16x32_bf16(aa0, bb1, acc01, 0, 0, 0);
      acc10 = __builtin_amdgcn_mfma_f32_16x16x32_bf16(aa1, bb0, acc10, 0, 0, 0);
      acc11 = __builtin_amdgcn_mfma_f32_16x16x32_bf16(aa1, bb1, acc11, 0, 0, 0);
    }
  }

  fv4 accs[2][2] = {{acc00, acc01}, {acc10, acc11}};
#pragma unroll
  for (int rb = 0; rb < 2; ++rb) {
#pragma unroll
    for (int cbl = 0; cbl < 2; ++cbl) {
#pragma unroll
      for (int j = 0; j < 4; ++j) {
        const int r = bm0 + wm + rb * 16 + (lane >> 4) * 4 + j;
        const int c = bn0 + wn + cbl * 16 + (lane & 15);
        if (r >= a.M) continue;
        const float v = accs[rb][cbl][j];
        if (a.epi == 1) {
          a.Cb[(long)r * a.ldc + c] = f2b(v);
        } else if (a.epi == 2) {
          const float x = tanhf(v + a.e0[c]);
          if (c < 512) a.Cf[(long)r * 512 + c] = x;
          else         a.Cf2[(long)r * 512 + (c - 512)] = x;
        } else {
          a.Cf[(long)r * a.ldc + c] = v + a.e0[c];
        }
      }
    }
  }
}

// ===========================================================================
// Dual batched GEMM 64x64, global_load_lds staging.
// EPI: 1 = s-epilogue (GT), 2 = raw K1/K2 (GK)
// ===========================================================================
struct GA2 {
  const u16* A1; const u16* A2; const u16* B1; const u16* B2;
  long lda, ldb, sAz, sBz;
  float* Cf; float* Cf2; u16* Cb;
  long ldc, sCz;
  int M, K;
  const float* e1; const float* e2; const float* e3;
  const float* e4; const float* e5; const float* e6;
};

__device__ __forceinline__ void gemm2_core(const GA2& a, u16* As1, u16* As2,
                                           u16* Bs1, u16* Bs2,
                                           int bx, int by, int bz, int t, int EPI) {
  const int z = bz;
  const int bm0 = bx * 64, bn0 = by * 64;
  const int lane = t & 63, w = t >> 6;
  const int wm = (w >> 1) * 32, wn = (w & 1) * 32;
  const u16* A1b = a.A1 + (long)z * a.sAz;
  const u16* A2b = a.A2 + (long)z * a.sAz;
  const u16* B1b = a.B1 + (long)z * a.sBz;
  const u16* B2b = a.B2 + (long)z * a.sBz;

  const int sr = t >> 3;
  const int swc = ((t & 7) ^ (sr & 7)) << 3;
  const long aoff0 = (long)(bm0 + sr) * a.lda + swc;
  const long aoff1 = (long)(bm0 + sr + 32) * a.lda + swc;
  const long boff0 = (long)(bn0 + sr) * a.ldb + swc;
  const long boff1 = (long)(bn0 + sr + 32) * a.ldb + swc;
  const u16 *a1p0 = A1b + aoff0, *a1p1 = A1b + aoff1;
  const u16 *a2p0 = A2b + aoff0, *a2p1 = A2b + aoff1;
  const u16 *b1p0 = B1b + boff0, *b1p1 = B1b + boff1;
  const u16 *b2p0 = B2b + boff0, *b2p1 = B2b + boff1;
  u16* lA10 = As1 + w * 512;  u16* lA11 = As1 + 2048 + w * 512;
  u16* lA20 = As2 + w * 512;  u16* lA21 = As2 + 2048 + w * 512;
  u16* lB10 = Bs1 + w * 512;  u16* lB11 = Bs1 + 2048 + w * 512;
  u16* lB20 = Bs2 + w * 512;  u16* lB21 = Bs2 + 2048 + w * 512;

  fv4 zero = {0.f, 0.f, 0.f, 0.f};
  fv4 p00 = zero, p01 = zero, p10 = zero, p11 = zero;
  fv4 q00 = zero, q01 = zero, q10 = zero, q11 = zero;
  const int r0 = lane & 15, kq8 = lane >> 4;
  const int nk = a.K >> 6;

  for (int kt = 0; kt < nk; ++kt) {
    __syncthreads();
    gll16(a1p0, lA10); gll16(a1p1, lA11);
    gll16(a2p0, lA20); gll16(a2p1, lA21);
    gll16(b1p0, lB10); gll16(b1p1, lB11);
    gll16(b2p0, lB20); gll16(b2p1, lB21);
    __syncthreads();
    a1p0 += 64; a1p1 += 64; a2p0 += 64; a2p1 += 64;
    b1p0 += 64; b1p1 += 64; b2p0 += 64; b2p1 += 64;
#pragma unroll
    for (int kc = 0; kc < 2; ++kc) {
      const int c8 = kq8 + 4 * kc;
      bh8 x0 = lds_rd(As1, wm + r0, c8);
      bh8 x1 = lds_rd(As1, wm + 16 + r0, c8);
      bh8 y0 = lds_rd(Bs1, wn + r0, c8);
      bh8 y1 = lds_rd(Bs1, wn + 16 + r0, c8);
      p00 = __builtin_amdgcn_mfma_f32_16x16x32_bf16(x0, y0, p00, 0, 0, 0);
      p01 = __builtin_amdgcn_mfma_f32_16x16x32_bf16(x0, y1, p01, 0, 0, 0);
      p10 = __builtin_amdgcn_mfma_f32_16x16x32_bf16(x1, y0, p10, 0, 0, 0);
      p11 = __builtin_amdgcn_mfma_f32_16x16x32_bf16(x1, y1, p11, 0, 0, 0);
      bh8 u0 = lds_rd(As2, wm + r0, c8);
      bh8 u1 = lds_rd(As2, wm + 16 + r0, c8);
      bh8 v0 = lds_rd(Bs2, wn + r0, c8);
      bh8 v1 = lds_rd(Bs2, wn + 16 + r0, c8);
      q00 = __builtin_amdgcn_mfma_f32_16x16x32_bf16(u0, v0, q00, 0, 0, 0);
      q01 = __builtin_amdgcn_mfma_f32_16x16x32_bf16(u0, v1, q01, 0, 0, 0);
      q10 = __builtin_amdgcn_mfma_f32_16x16x32_bf16(u1, v0, q10, 0, 0, 0);
      q11 = __builtin_amdgcn_mfma_f32_16x16x32_bf16(u1, v1, q11, 0, 0, 0);
    }
  }

  fv4 pa[2][2] = {{p00, p01}, {p10, p11}};
  fv4 qa[2][2] = {{q00, q01}, {q10, q11}};
#pragma unroll
  for (int rb = 0; rb < 2; ++rb) {
#pragma unroll
    for (int cbl = 0; cbl < 2; ++cbl) {
#pragma unroll
      for (int j = 0; j < 4; ++j) {
        const int r = bm0 + wm + rb * 16 + (lane >> 4) * 4 + j;
        const int c = bn0 + wn + cbl * 16 + (lane & 15);
        const float v1 = pa[rb][cbl][j];
        const float v2 = qa[rb][cbl][j];
        if (EPI == 2) {  // raw K1/K2
          const long idx = (long)z * a.sCz + (long)r * a.ldc + c;
          a.Cf[idx] = v1;
          a.Cf2[idx] = v2;
        } else {  // s: v1=T1, v2=T2
          const int lh = z * 256 + r;
          const int bl = z * 32 + (r >> 3);
          const float G2d = a.e1[c], B2d = a.e2[c];
          const float gv = a.e3[(long)bl * 512 + c];
          const float bev = a.e4[(long)bl * 512 + c];
          const float sv = v1 + B2d + G2d * (gv * v2 + bev * a.e5[lh] - a.e6[lh]);
          a.Cb[(long)z * a.sCz + (long)r * a.ldc + c] = f2b(sv);
        }
      }
    }
  }
}

// ===========================================================================
// Elementwise / transpose units (verified)
// ===========================================================================
__device__ __forceinline__ void tpf32_unit(const float* src, long lds, u16* dst, long ldd,
                                           int tr, int tc, int t, float T[64][65]) {
  const int c = t & 63, rg = t >> 6;
#pragma unroll 4
  for (int i = 0; i < 16; ++i) {
    const int r = rg + 4 * i;
    T[r][c] = src[(long)(tr * 64 + r) * lds + tc * 64 + c];
  }
  __syncthreads();
#pragma unroll 4
  for (int i = 0; i < 16; ++i) {
    const int r = rg + 4 * i;
    dst[(long)(tc * 64 + r) * ldd + tr * 64 + c] = f2b(T[c][r]);
  }
}

__device__ __forceinline__ void tpb16_unit(const u16* src, u16* dst, int b, int w32,
                                           int t, float T[64][65]) {
  const int tr = w32 >> 3, tc = w32 & 7;
  const u16* s = src + (long)b * 131072;
  u16* d = dst + (long)b * 131072;
  const int c = t & 63, rg = t >> 6;
#pragma unroll 4
  for (int i = 0; i < 16; ++i) {
    const int r = rg + 4 * i;
    T[r][c] = b2f(s[(long)(tr * 64 + r) * 512 + tc * 64 + c]);
  }
  __syncthreads();
#pragma unroll 4
  for (int i = 0; i < 16; ++i) {
    const int r = rg + 4 * i;
    d[(long)(tc * 64 + r) * 256 + tr * 64 + c] = f2b(T[c][r]);
  }
}

__device__ __forceinline__ void cvt_unit(const float* s, u16* d, long blk, int t) {
  const long idx = blk * 2048 + t * 8;
  const float4 x0 = ld4(s + idx), x1 = ld4(s + idx + 4);
  const float v[8] = {x0.x, x0.y, x0.z, x0.w, x1.x, x1.y, x1.z, x1.w};
  *(uint4*)(d + idx) = pack8(v);
}

__device__ __forceinline__ void ln_unit(const FA& f, int u, int t) {
  const int lane = t & 63, e = lane * 8;
  const int row = u * 4 + (t >> 6);
  const float* p = f.condpre + (long)row * 512 + e;
  const float4 x0 = ld4(p), x1 = ld4(p + 4);
  float v[8] = {x0.x, x0.y, x0.z, x0.w, x1.x, x1.y, x1.z, x1.w};
  float s = 0.f, sq = 0.f;
#pragma unroll
  for (int i = 0; i < 8; ++i) { s += v[i]; sq += v[i] * v[i]; }
#pragma unroll
  for (int m = 1; m < 64; m <<= 1) { s += __shfl_xor(s, m); sq += __shfl_xor(sq, m); }
  const float mu = s * (1.f / 512.f);
  const float iv = rsqrtf(sq * (1.f / 512.f) - mu * mu + LN_EPS);
  const float4 g0 = ld4(f.ln1g + e), g1 = ld4(f.ln1g + e + 4);
  const float4 b0 = ld4(f.ln1b + e), b1 = ld4(f.ln1b + e + 4);
  const float gg[8] = {g0.x, g0.y, g0.z, g0.w, g1.x, g1.y, g1.z, g1.w};
  const float bb[8] = {b0.x, b0.y, b0.z, b0.w, b1.x, b1.y, b1.z, b1.w};
  float o[8], osq[8];
#pragma unroll
  for (int i = 0; i < 8; ++i) {
    o[i] = (v[i] - mu) * iv * gg[i] + bb[i];
    osq[i] = o[i] * o[i];
  }
  *(uint4*)(f.cb_bf + (long)row * 512 + e) = pack8(o);
  *(uint4*)(f.cbsq_bf + (long)row * 512 + e) = pack8(osq);
}

__device__ __forceinline__ void a96_unit(const FA& f, int u, int t) {
  const int lane = t & 63, e = lane * 8;
  const int bl = u * 4 + (t >> 6);
  const int b = bl >> 5, l = bl & 31;
  const float4 ga0 = ld4(f.gam + (long)bl * 512 + e), ga1 = ld4(f.gam + (long)bl * 512 + e + 4);
  const float4 be0 = ld4(f.bet + (long)bl * 512 + e), be1 = ld4(f.bet + (long)bl * 512 + e + 4);
  const float gv[8] = {ga0.x, ga0.y, ga0.z, ga0.w, ga1.x, ga1.y, ga1.z, ga1.w};
  const float bv[8] = {be0.x, be0.y, be0.z, be0.w, be1.x, be1.y, be1.z, be1.w};
  float gg[8], gb[8]; float s1 = 0.f, s2 = 0.f;
#pragma unroll
  for (int i = 0; i < 8; ++i) {
    gg[i] = gv[i] * gv[i]; gb[i] = gv[i] * bv[i];
    s1 += bv[i]; s2 += bv[i] * bv[i];
  }
  const long basei = ((long)b * 96 + l) * 512 + e;
  *(uint4*)(f.A96_bf + basei) = pack8(gv);
  *(uint4*)(f.A96_bf + basei + 32 * 512) = pack8(gb);
  *(uint4*)(f.A96_bf + basei + 64 * 512) = pack8(gg);
#pragma unroll
  for (int m = 1; m < 64; m <<= 1) { s1 += __shfl_xor(s1, m); s2 += __shfl_xor(s2, m); }
  if (lane == 0) { f.sum_be[bl] = s1; f.sum_be2[bl] = s2; }
}

__device__ __forceinline__ void csum_unit(const FA& f, int u, int t) {
  const int lane = t & 63, e = lane * 8;
  const int lh = u * 4 + (t >> 6);
  const int bl = lh >> 3;
  const uint4 up = *(const uint4*)(f.u_bf + (long)lh * 512 + e);
  const u16* us = (const u16*)&up;
  const float4 be0 = ld4(f.bet + (long)bl * 512 + e), be1 = ld4(f.bet + (long)bl * 512 + e + 4);
  const float4 G0 = ld4(f.ln2g + e), G1 = ld4(f.ln2g + e + 4);
  const float4 B0 = ld4(f.ln2b + e), B1 = ld4(f.ln2b + e + 4);
  const float bv[8] = {be0.x, be0.y, be0.z, be0.w, be1.x, be1.y, be1.z, be1.w};
  const float Gv[8] = {G0.x, G0.y, G0.z, G0.w, G1.x, G1.y, G1.z, G1.w};
  const float Bv[8] = {B0.x, B0.y, B0.z, B0.w, B1.x, B1.y, B1.z, B1.w};
  float a2 = 0.f, a3 = 0.f, a4 = 0.f;
#pragma unroll
  for (int i = 0; i < 8; ++i) {
    const float uu = b2f(us[i]);
    const float t1 = Gv[i] * uu;
    a2 += bv[i] * t1; a3 += t1; a4 += Bv[i] * uu;
  }
#pragma unroll
  for (int m = 1; m < 64; m <<= 1) {
    a2 += __shfl_xor(a2, m); a3 += __shfl_xor(a3, m); a4 += __shfl_xor(a4, m);
  }
  if (lane == 0) { f.c2[lh] = a2; f.c3[lh] = a3; f.c4[lh] = a4; }
}

// softmax + logits assembly (reads raw K1/K2)
__device__ __forceinline__ void softmax2_unit(const FA& f, int u, int t) {
  const int lane = t & 63, e = lane * 4;
  const int lh = u * 4 + (t >> 6);
  const int b = lh >> 8, l = (lh >> 3) & 31, bl = lh >> 3;
  const float4 k1 = ld4(f.K1 + (long)lh * 256 + e);
  const float4 k2 = ld4(f.K2 + (long)lh * 256 + e);
  const float* Pb = f.P + ((long)b * 96 + l) * 256 + e;
  const float4 p0 = ld4(Pb), pgb = ld4(Pb + 32 * 256), pg2 = ld4(Pb + 64 * 256);
  const float sbe = f.sum_be[bl], sbe2 = f.sum_be2[bl];
  const float C2 = f.c2[lh], C3 = f.c3[lh], C4 = f.c4[lh];
  const float k1s[4] = {k1.x, k1.y, k1.z, k1.w};
  const float k2s[4] = {k2.x, k2.y, k2.z, k2.w};
  const float p0s[4] = {p0.x, p0.y, p0.z, p0.w};
  const float pgbs[4] = {pgb.x, pgb.y, pgb.z, pgb.w};
  const float pg2s[4] = {pg2.x, pg2.y, pg2.z, pg2.w};
  float mu[4], iv[4], lgs[4];
#pragma unroll
  for (int i = 0; i < 4; ++i) {
    mu[i] = (p0s[i] + sbe) * (1.f / 512.f);
    const float msq = (pg2s[i] + 2.f * pgbs[i] + sbe2) * (1.f / 512.f);
    iv[i] = rsqrtf(msq - mu[i] * mu[i] + LN_EPS);
    lgs[i] = k1s[i] + C4 + iv[i] * (k2s[i] + C2 - mu[i] * C3);
  }
  float mx = fmaxf(fmaxf(lgs[0], lgs[1]), fmaxf(lgs[2], lgs[3]));
#pragma unroll
  for (int m = 1; m < 64; m <<= 1) mx = fmaxf(mx, __shfl_xor(mx, m));
  float ex[4]; float z = 0.f;
#pragma unroll
  for (int i = 0; i < 4; ++i) { ex[i] = expf(lgs[i] - mx); z += ex[i]; }
#pragma unroll
  for (int m = 1; m < 64; m <<= 1) z += __shfl_xor(z, m);
  const float rz = 1.f / z;
  float wv[4], w1v[4]; float s1 = 0.f, s2 = 0.f;
#pragma unroll
  for (int i = 0; i < 4; ++i) {
    wv[i] = ex[i] * rz;
    w1v[i] = wv[i] * iv[i];
    s1 += w1v[i]; s2 += w1v[i] * mu[i];
  }
  uint2 wp, w1p;
  wp.x = pk2(wv[0], wv[1]); wp.y = pk2(wv[2], wv[3]);
  w1p.x = pk2(w1v[0], w1v[1]); w1p.y = pk2(w1v[2], w1v[3]);
  *(uint2*)(f.w_bf + (long)lh * 256 + e) = wp;
  *(uint2*)(f.W1_bf + (long)lh * 256 + e) = w1p;
#pragma unroll
  for (int m = 1; m < 64; m <<= 1) { s1 += __shfl_xor(s1, m); s2 += __shfl_xor(s2, m); }
  if (lane == 0) { f.S1[lh] = s1; f.S2[lh] = s2; }
}

// ===========================================================================
// Phase kernels (7 dispatches, round-7 DAG)
// ===========================================================================
// A: G2-f32(512) + G1a-f32(128) + G1b-f32(64) + k cvt(1024) + Wv(128) + Wfc(128)
//    + WkT(64) + kT(512) = 2560
__global__ __launch_bounds__(256) void pA_k(FA f) {
  __shared__ __align__(16) char smem[16704];
  u16* As = (u16*)smem;
  u16* Bs = (u16*)(smem + 8192);
  float (*T)[65] = (float(*)[65])smem;
  const int u = blockIdx.x, t = threadIdx.x;
  if (u < 512) {
    GAF a = {}; a.Af = f.k; a.Bf = f.Wvp; a.lda = 512; a.ldb = 512;
    a.Cf = f.condpre; a.ldc = 512; a.M = 4096; a.K = 512; a.epi = 4; a.e0 = f.bvp;
    gemm_core_f32(a, As, Bs, u % 64, u / 64, t);
  } else if (u < 640) {
    const int r = u - 512;
    GAF a = {}; a.Af = f.q; a.Bf = f.Wg; a.lda = 512; a.ldb = 512;
    a.Cf = f.gam; a.Cf2 = f.bet; a.ldc = 512; a.M = 512; a.K = 512; a.epi = 2; a.e0 = f.bg;
    gemm_core_f32(a, As, Bs, r % 8, r / 8, t);
  } else if (u < 704) {
    const int r = u - 640;
    GAF a = {}; a.Af = f.q; a.Bf = f.Wq; a.lda = 512; a.ldb = 512;
    a.Cb = f.qh_bf; a.ldc = 512; a.M = 512; a.K = 512; a.epi = 1;
    gemm_core_f32(a, As, Bs, r % 8, r / 8, t);
  } else if (u < 1728) {
    cvt_unit(f.k, f.k_bf, u - 704, t);
  } else if (u < 1856) {
    cvt_unit(f.Wv, f.Wv_bf, u - 1728, t);
  } else if (u < 1984) {
    cvt_unit(f.Wfc, f.Wfc_bf, u - 1856, t);
  } else if (u < 2048) {
    const int tt = u - 1984;
    tpf32_unit(f.Wk, 512, f.WkT_bf, 512, tt >> 3, tt & 7, t, T);
  } else {
    const int tt = u - 2048;
    const int b = tt >> 5, w32 = tt & 31;
    tpf32_unit(f.k + (long)b * 131072, 512, f.kT_bf + (long)b * 131072, 256,
               w32 >> 3, w32 & 7, t, T);
  }
}

// B: LN(1024) + A96(128) + Gu·w1(512) = 1664
__global__ __launch_bounds__(256) void pB_k(FA f) {
  __shared__ __align__(16) char smem[16384];
  u16* As = (u16*)smem;
  u16* Bs = (u16*)(smem + 8192);
  const int u = blockIdx.x, t = threadIdx.x;
  if (u < 1024) {
    ln_unit(f, u, t);
  } else if (u < 1152) {
    a96_unit(f, u - 1024, t);
  } else {
    const int r = u - 1152;
    GA a = {}; a.A = f.qh_bf; a.lda = 512; a.sAz = 64;
    a.B = f.WkT_bf; a.ldb = 512; a.sBz = 64;
    a.Cb = f.u_bf; a.Cb2 = f.w1_bf; a.ldc = 512; a.M = 512; a.K = 64; a.epi = 6;
    a.e0 = f.gam; a.e1 = f.ln2g;
    gemm_core(a, As, Bs, r % 8, (r / 8) % 8, r / 64, t);
  }
}

// C: GP(128) + cbT(512) + csum(1024) + GK-raw(256) = 1920
__global__ __launch_bounds__(256) void pC_k(FA f) {
  __shared__ __align__(16) char smem[32768];
  const int u = blockIdx.x, t = threadIdx.x;
  if (u < 128) {
    u16* As = (u16*)smem; u16* Bs = (u16*)(smem + 8192);
    GA a = {}; a.A = f.A96_bf; a.lda = 512; a.sAz = 96 * 512;
    a.B = f.cb_bf; a.Balt = f.cbsq_bf; a.ldb = 512; a.sBz = 256 * 512;
    a.Cf = f.P; a.ldc = 256; a.sCz = 96 * 256; a.M = 96; a.K = 512; a.epi = 0;
    gemm_core(a, As, Bs, u % 2, (u / 2) % 4, u / 8, t);
  } else if (u < 640) {
    float (*T)[65] = (float(*)[65])smem;
    const int tt = u - 128;
    tpb16_unit(f.cb_bf, f.cbT_bf, tt >> 5, tt & 31, t, T);
  } else if (u < 1664) {
    csum_unit(f, u - 640, t);
  } else {
    const int r = u - 1664;
    u16* As1 = (u16*)smem; u16* As2 = (u16*)(smem + 8192);
    u16* Bs1 = (u16*)(smem + 16384); u16* Bs2 = (u16*)(smem + 24576);
    GA2 d = {};
    d.A1 = f.u_bf; d.A2 = f.w1_bf; d.B1 = f.k_bf; d.B2 = f.cb_bf;
    d.lda = 512; d.ldb = 512; d.sAz = 256 * 512; d.sBz = 256 * 512;
    d.Cf = f.K1; d.Cf2 = f.K2; d.ldc = 256; d.sCz = 256 * 256; d.M = 256; d.K = 512;
    gemm2_core(d, As1, As2, Bs1, Bs2, r % 4, (r / 4) % 4, r / 16, t, 2);
  }
}

// D: softmax + logits assembly (1024)
__global__ __launch_bounds__(256) void pD_k(FA f) {
  softmax2_unit(f, blockIdx.x, threadIdx.x);
}

// E: GT (512)
__global__ __launch_bounds__(256) void pE_k(FA f) {
  __shared__ __align__(16) char smem[32768];
  u16* As1 = (u16*)smem; u16* As2 = (u16*)(smem + 8192);
  u16* Bs1 = (u16*)(smem + 16384); u16* Bs2 = (u16*)(smem + 24576);
  const int u = blockIdx.x, t = threadIdx.x;
  GA2 d = {};
  d.A1 = f.w_bf; d.A2 = f.W1_bf; d.B1 = f.kT_bf; d.B2 = f.cbT_bf;
  d.lda = 256; d.ldb = 256; d.sAz = 256 * 256; d.sBz = 512 * 256;
  d.Cb = f.s_bf; d.ldc = 512; d.sCz = 256 * 512; d.M = 256; d.K = 256;
  d.e1 = f.ln2g; d.e2 = f.ln2b; d.e3 = f.gam; d.e4 = f.bet; d.e5 = f.S1; d.e6 = f.S2;
  gemm2_core(d, As1, As2, Bs1, Bs2, u % 4, (u / 4) % 8, u / 32, t, 1);
}

// F: attn = s_h @ Wv_h^T (64)
__global__ __launch_bounds__(256) void pF_k(FA f) {
  __shared__ __align__(16) char smem[16384];
  u16* As = (u16*)smem; u16* Bs = (u16*)(smem + 8192);
  const int u = blockIdx.x, t = threadIdx.x;
  GA a = {}; a.A = f.s_bf; a.lda = 4096; a.sAz = 512;
  a.B = f.Wv_bf; a.ldb = 512; a.sBz = 64 * 512;
  a.Cb = f.attn_bf; a.ldc = 512; a.sCz = 64; a.M = 512; a.K = 512; a.epi = 1;
  gemm_core(a, As, Bs, u % 8, 0, u / 8, t);
}

// G: out = attn @ Wfc^T (64)
__global__ __launch_bounds__(256) void pG_k(FA f) {
  __shared__ __align__(16) char smem[16384];
  u16* As = (u16*)smem; u16* Bs = (u16*)(smem + 8192);
  const int u = blockIdx.x, t = threadIdx.x;
  GA a = {}; a.A = f.attn_bf; a.lda = 512;
  a.B = f.Wfc_bf; a.ldb = 512;
  a.Cf = f.out; a.ldc = 512; a.M = 512; a.K = 512; a.epi = 0;
  gemm_core(a, As, Bs, u % 8, u / 8, 0, t);
}

}  // namespace

extern "C" void kernel_launch(void* const* d_in, const int* in_sizes, int n_in,
                              void* d_out, int out_size, void* d_ws, size_t ws_size,
                              hipStream_t stream) {
  (void)in_sizes; (void)n_in; (void)out_size;
  FA fa;
  fa.q    = (const float*)d_in[0];
  fa.k    = (const float*)d_in[1];
  fa.Wq   = (const float*)d_in[3];
  fa.Wk   = (const float*)d_in[4];
  fa.Wv   = (const float*)d_in[5];
  fa.Wfc  = (const float*)d_in[6];
  fa.Wg   = (const float*)d_in[7];
  fa.bg   = (const float*)d_in[8];
  fa.Wvp  = (const float*)d_in[9];
  fa.bvp  = (const float*)d_in[10];
  fa.ln1g = (const float*)d_in[11];
  fa.ln1b = (const float*)d_in[12];
  fa.ln2g = (const float*)d_in[13];
  fa.ln2b = (const float*)d_in[14];
  fa.out  = (float*)d_out;

  char* base = (char*)d_ws;
  size_t off = 0;
  auto au16 = [&](size_t n) -> u16* {
    u16* p = (u16*)(base + off); off = (off + n * 2 + 255) & ~(size_t)255; return p;
  };
  auto af32 = [&](size_t n) -> float* {
    float* p = (float*)(base + off); off = (off + n * 4 + 255) & ~(size_t)255; return p;
  };
  (void)au16(262144);               // layout parity (unused)
  (void)au16(524288);
  (void)au16(262144);
  (void)au16(262144);
  fa.WkT_bf  = au16(262144);
  fa.Wv_bf   = au16(262144);
  fa.Wfc_bf  = au16(262144);
  fa.k_bf    = au16(2097152);
  fa.kT_bf   = au16(2097152);
  fa.qh_bf   = au16(262144);
  fa.gam     = af32(262144);
  fa.bet     = af32(262144);
  fa.condpre = af32(2097152);       // K1 = first half, K2 = second half (post-LN)
  fa.cb_bf   = au16(2097152);
  fa.cbT_bf  = au16(2097152);
  fa.u_bf    = au16(2097152);
  fa.w1_bf   = au16(2097152);
  fa.c2      = af32(4096);
  fa.c3      = af32(4096);
  fa.c4      = af32(4096);
  fa.A96_bf  = au16(16 * 96 * 512);
  fa.sum_be  = af32(512);
  fa.sum_be2 = af32(512);
  fa.P       = af32(16 * 96 * 256);
  float* sbuf   = af32(1048576);
  float* logits = af32(1048576);    // holds cb^2 (bf16) from LN
  fa.w_bf    = au16(1048576);
  fa.W1_bf   = au16(1048576);
  fa.S1      = af32(4096);
  fa.S2      = af32(4096);
  fa.attn_bf = au16(262144);
  const size_t need = off;
  fa.s_bf    = (u16*)sbuf;
  fa.cbsq_bf = (u16*)logits;
  fa.K1      = fa.condpre;          // condpre dead after LN (phase B)
  fa.K2      = fa.condpre + 1048576;

  if (ws_size < need) return;

  const dim3 blk(256);
  pA_k<<<dim3(2560), blk, 0, stream>>>(fa);
  pB_k<<<dim3(1664), blk, 0, stream>>>(fa);
  pC_k<<<dim3(1920), blk, 0, stream>>>(fa);
  pD_k<<<dim3(1024), blk, 0, stream>>>(fa);
  pE_k<<<dim3(512),  blk, 0, stream>>>(fa);
  pF_k<<<dim3(64),   blk, 0, stream>>>(fa);
  pG_k<<<dim3(64),   blk, 0, stream>>>(fa);
}

// Round 11
// 76.285 us; speedup vs baseline: 1.5921x; 1.0066x over previous
//
#include <hip/hip_runtime.h>
#include <math.h>

namespace {
constexpr float LN_EPS = 1e-5f;

typedef unsigned short u16;
typedef __attribute__((ext_vector_type(8))) short bh8;
typedef __attribute__((ext_vector_type(4))) float fv4;

__device__ __forceinline__ float4 ld4(const float* p) { return *reinterpret_cast<const float4*>(p); }

__device__ __forceinline__ float b2f(u16 x) {
  union { float f; unsigned u; } c; c.u = ((unsigned)x) << 16; return c.f;
}
__device__ __forceinline__ u16 f2b(float f) {  // RTN-even
  union { float f; unsigned u; } c; c.f = f;
  unsigned u = c.u;
  u += 0x7FFFu + ((u >> 16) & 1u);
  return (u16)(u >> 16);
}
__device__ __forceinline__ unsigned pk2(float a, float b) {
  return (unsigned)f2b(a) | ((unsigned)f2b(b) << 16);
}
__device__ __forceinline__ uint4 pack8(const float* v) {
  uint4 r; r.x = pk2(v[0], v[1]); r.y = pk2(v[2], v[3]); r.z = pk2(v[4], v[5]); r.w = pk2(v[6], v[7]);
  return r;
}

// XOR-swizzled LDS tile access: [R][64] u16, 16B slots, c8 ^= row&7
__device__ __forceinline__ bh8 lds_rd(const u16* S, int row, int c8) {
  return *(const bh8*)&S[row * 64 + ((c8 ^ (row & 7)) << 3)];
}

// async global->LDS, 16B per lane; LDS dest = wave-uniform base + lane*16B.
// Swizzle achieved by pre-swizzling the per-lane GLOBAL column (m173 pattern).
__device__ __forceinline__ void gll16(const u16* g, u16* l) {
  __builtin_amdgcn_global_load_lds((const __attribute__((address_space(1))) void*)g,
                                   (__attribute__((address_space(3))) void*)l, 16, 0, 0);
}

struct FA {
  const float *q, *k, *Wq, *Wk, *Wv, *Wfc, *Wg, *bg, *Wvp, *bvp;
  const float *ln1g, *ln1b, *ln2g, *ln2b;
  float* out;
  u16 *WkT_bf, *Wv_bf, *Wfc_bf, *k_bf, *kT_bf, *qh_bf;
  float *gam, *bet, *condpre;
  u16 *cb_bf, *cbT_bf, *u_bf, *w1_bf;
  float *c2, *c3, *c4;
  u16* A96_bf;
  float *sum_be, *sum_be2, *P;
  u16* s_bf;
  u16 *cbsq_bf, *w_bf, *W1_bf;
  float *S1, *S2;
  u16* attn_bf;
  float *K1, *K2;
};

// ===========================================================================
// bf16 GEMM core 64x64, global_load_lds staging. epi: 0 f32, 1 bf16,
// 5 u-remap, 6 u-remap + fused w1
// ===========================================================================
struct GA {
  const u16* A; const u16* B; const u16* Balt;
  long lda, ldb, sAz, sBz;
  float* Cf; u16* Cb; u16* Cb2;
  long ldc, sCz;
  int M, K, epi;
  const float* e0; const float* e1;
};

__device__ __forceinline__ void gemm_core(const GA& a, u16* As, u16* Bs,
                                          int bx, int by, int bz, int t) {
  const int z = bz;
  const int bm0 = bx * 64, bn0 = by * 64;
  const int lane = t & 63, w = t >> 6;
  const int wm = (w >> 1) * 32, wn = (w & 1) * 32;
  const u16* Ab = a.A + (long)z * a.sAz;
  const u16* Bbase = (a.Balt != nullptr && bm0 >= 64) ? a.Balt : a.B;
  const u16* Bb = Bbase + (long)z * a.sBz;

  const int sr = t >> 3;                        // LDS row-in-block 0..31
  const int swc = ((t & 7) ^ (sr & 7)) << 3;    // pre-swizzled source col (elems)
  int ar0 = bm0 + sr;      if (ar0 > a.M - 1) ar0 = a.M - 1;
  int ar1 = bm0 + sr + 32; if (ar1 > a.M - 1) ar1 = a.M - 1;
  const u16* ap0 = Ab + (long)ar0 * a.lda + swc;
  const u16* ap1 = Ab + (long)ar1 * a.lda + swc;
  const u16* bp0 = Bb + (long)(bn0 + sr) * a.ldb + swc;
  const u16* bp1 = Bb + (long)(bn0 + sr + 32) * a.ldb + swc;
  u16* lA0 = As + w * 512;           // wave-uniform LDS bases (linear dest)
  u16* lA1 = As + 2048 + w * 512;
  u16* lB0 = Bs + w * 512;
  u16* lB1 = Bs + 2048 + w * 512;

  fv4 zero = {0.f, 0.f, 0.f, 0.f};
  fv4 acc00 = zero, acc01 = zero, acc10 = zero, acc11 = zero;
  const int r0 = lane & 15, kq8 = lane >> 4;
  const int nk = a.K >> 6;

  for (int kt = 0; kt < nk; ++kt) {
    __syncthreads();
    gll16(ap0, lA0); gll16(ap1, lA1);
    gll16(bp0, lB0); gll16(bp1, lB1);
    __syncthreads();   // compiler drains vmcnt before barrier -> LDS ready
    ap0 += 64; ap1 += 64; bp0 += 64; bp1 += 64;
#pragma unroll
    for (int kc = 0; kc < 2; ++kc) {
      const int c8 = kq8 + 4 * kc;
      bh8 aa0 = lds_rd(As, wm + r0, c8);
      bh8 aa1 = lds_rd(As, wm + 16 + r0, c8);
      bh8 bb0 = lds_rd(Bs, wn + r0, c8);
      bh8 bb1 = lds_rd(Bs, wn + 16 + r0, c8);
      acc00 = __builtin_amdgcn_mfma_f32_16x16x32_bf16(aa0, bb0, acc00, 0, 0, 0);
      acc01 = __builtin_amdgcn_mfma_f32_16x16x32_bf16(aa0, bb1, acc01, 0, 0, 0);
      acc10 = __builtin_amdgcn_mfma_f32_16x16x32_bf16(aa1, bb0, acc10, 0, 0, 0);
      acc11 = __builtin_amdgcn_mfma_f32_16x16x32_bf16(aa1, bb1, acc11, 0, 0, 0);
    }
  }

  fv4 accs[2][2] = {{acc00, acc01}, {acc10, acc11}};
#pragma unroll
  for (int rb = 0; rb < 2; ++rb) {
#pragma unroll
    for (int cbl = 0; cbl < 2; ++cbl) {
#pragma unroll
      for (int j = 0; j < 4; ++j) {
        const int r = bm0 + wm + rb * 16 + (lane >> 4) * 4 + j;
        const int c = bn0 + wn + cbl * 16 + (lane & 15);
        if (r >= a.M) continue;
        const float v = accs[rb][cbl][j];
        if (a.epi == 0) {
          a.Cf[(long)z * a.sCz + (long)r * a.ldc + c] = v;
        } else if (a.epi == 1) {
          a.Cb[(long)z * a.sCz + (long)r * a.ldc + c] = f2b(v);
        } else if (a.epi == 5) {
          a.Cb[((long)r * 8 + z) * a.ldc + c] = f2b(v * 0.125f);
        } else {  // 6: u remap + fused w1
          const u16 ub = f2b(v * 0.125f);
          const long orow = (long)r * 8 + z;
          a.Cb[orow * 512 + c] = ub;
          const float uu = b2f(ub);
          const float t1 = a.e1[c] * uu;
          a.Cb2[orow * 512 + c] = f2b(a.e0[(long)r * 512 + c] * t1);
        }
      }
    }
  }
}

// ===========================================================================
// f32-staging GEMM core 64x64 (verified; conversion in staging).
// epi: 1 bf16, 2 film, 4 +bias
// ===========================================================================
struct GAF {
  const float* Af; const float* Bf;
  long lda, ldb;
  float* Cf; u16* Cb; float* Cf2;
  long ldc;
  int M, K, epi;
  const float* e0;
};

__device__ __forceinline__ void gemm_core_f32(const GAF& a, u16* As, u16* Bs,
                                              int bx, int by, int t) {
  const int bm0 = bx * 64, bn0 = by * 64;
  const int lane = t & 63, w = t >> 6;
  const int wm = (w >> 1) * 32, wn = (w & 1) * 32;
  const int sr = t >> 3, sc8 = t & 7, sc = sc8 * 8;
  int ar0 = bm0 + sr;      if (ar0 > a.M - 1) ar0 = a.M - 1;
  int ar1 = bm0 + sr + 32; if (ar1 > a.M - 1) ar1 = a.M - 1;
  const float* ap0 = a.Af + (long)ar0 * a.lda + sc;
  const float* ap1 = a.Af + (long)ar1 * a.lda + sc;
  const float* bp0 = a.Bf + (long)(bn0 + sr) * a.ldb + sc;
  const float* bp1 = a.Bf + (long)(bn0 + sr + 32) * a.ldb + sc;
  const int iA0 = sr * 64 + ((sc8 ^ (sr & 7)) << 3);
  const int iA1 = iA0 + 32 * 64;

  fv4 zero = {0.f, 0.f, 0.f, 0.f};
  fv4 acc00 = zero, acc01 = zero, acc10 = zero, acc11 = zero;
  const int r0 = lane & 15, kq8 = lane >> 4;
  const int nk = a.K >> 6;

  float4 xa0 = ld4(ap0), xa1 = ld4(ap0 + 4), xa2 = ld4(ap1), xa3 = ld4(ap1 + 4);
  float4 xb0 = ld4(bp0), xb1 = ld4(bp0 + 4), xb2 = ld4(bp1), xb3 = ld4(bp1 + 4);
  for (int kt = 0; kt < nk; ++kt) {
    __syncthreads();
    {
      const float v0[8] = {xa0.x, xa0.y, xa0.z, xa0.w, xa1.x, xa1.y, xa1.z, xa1.w};
      const float v1[8] = {xa2.x, xa2.y, xa2.z, xa2.w, xa3.x, xa3.y, xa3.z, xa3.w};
      const float v2[8] = {xb0.x, xb0.y, xb0.z, xb0.w, xb1.x, xb1.y, xb1.z, xb1.w};
      const float v3[8] = {xb2.x, xb2.y, xb2.z, xb2.w, xb3.x, xb3.y, xb3.z, xb3.w};
      *(uint4*)&As[iA0] = pack8(v0);
      *(uint4*)&As[iA1] = pack8(v1);
      *(uint4*)&Bs[iA0] = pack8(v2);
      *(uint4*)&Bs[iA1] = pack8(v3);
    }
    __syncthreads();
    if (kt + 1 < nk) {
      ap0 += 64; ap1 += 64; bp0 += 64; bp1 += 64;
      xa0 = ld4(ap0); xa1 = ld4(ap0 + 4); xa2 = ld4(ap1); xa3 = ld4(ap1 + 4);
      xb0 = ld4(bp0); xb1 = ld4(bp0 + 4); xb2 = ld4(bp1); xb3 = ld4(bp1 + 4);
    }
#pragma unroll
    for (int kc = 0; kc < 2; ++kc) {
      const int c8 = kq8 + 4 * kc;
      bh8 aa0 = lds_rd(As, wm + r0, c8);
      bh8 aa1 = lds_rd(As, wm + 16 + r0, c8);
      bh8 bb0 = lds_rd(Bs, wn + r0, c8);
      bh8 bb1 = lds_rd(Bs, wn + 16 + r0, c8);
      acc00 = __builtin_amdgcn_mfma_f32_16x16x32_bf16(aa0, bb0, acc00, 0, 0, 0);
      acc01 = __builtin_amdgcn_mfma_f32_16x16x32_bf16(aa0, bb1, acc01, 0, 0, 0);
      acc10 = __builtin_amdgcn_mfma_f32_16x16x32_bf16(aa1, bb0, acc10, 0, 0, 0);
      acc11 = __builtin_amdgcn_mfma_f32_16x16x32_bf16(aa1, bb1, acc11, 0, 0, 0);
    }
  }

  fv4 accs[2][2] = {{acc00, acc01}, {acc10, acc11}};
#pragma unroll
  for (int rb = 0; rb < 2; ++rb) {
#pragma unroll
    for (int cbl = 0; cbl < 2; ++cbl) {
#pragma unroll
      for (int j = 0; j < 4; ++j) {
        const int r = bm0 + wm + rb * 16 + (lane >> 4) * 4 + j;
        const int c = bn0 + wn + cbl * 16 + (lane & 15);
        if (r >= a.M) continue;
        const float v = accs[rb][cbl][j];
        if (a.epi == 1) {
          a.Cb[(long)r * a.ldc + c] = f2b(v);
        } else if (a.epi == 2) {
          const float x = tanhf(v + a.e0[c]);
          if (c < 512) a.Cf[(long)r * 512 + c] = x;
          else         a.Cf2[(long)r * 512 + (c - 512)] = x;
        } else {
          a.Cf[(long)r * a.ldc + c] = v + a.e0[c];
        }
      }
    }
  }
}

// ===========================================================================
// Dual batched GEMM 64x64, global_load_lds staging.
// EPI: 1 = s-epilogue (GT), 2 = raw K1/K2 (GK)
// ===========================================================================
struct GA2 {
  const u16* A1; const u16* A2; const u16* B1; const u16* B2;
  long lda, ldb, sAz, sBz;
  float* Cf; float* Cf2; u16* Cb;
  long ldc, sCz;
  int M, K;
  const float* e1; const float* e2; const float* e3;
  const float* e4; const float* e5; const float* e6;
};

__device__ __forceinline__ void gemm2_core(const GA2& a, u16* As1, u16* As2,
                                           u16* Bs1, u16* Bs2,
                                           int bx, int by, int bz, int t, int EPI) {
  const int z = bz;
  const int bm0 = bx * 64, bn0 = by * 64;
  const int lane = t & 63, w = t >> 6;
  const int wm = (w >> 1) * 32, wn = (w & 1) * 32;
  const u16* A1b = a.A1 + (long)z * a.sAz;
  const u16* A2b = a.A2 + (long)z * a.sAz;
  const u16* B1b = a.B1 + (long)z * a.sBz;
  const u16* B2b = a.B2 + (long)z * a.sBz;

  const int sr = t >> 3;
  const int swc = ((t & 7) ^ (sr & 7)) << 3;
  const long aoff0 = (long)(bm0 + sr) * a.lda + swc;
  const long aoff1 = (long)(bm0 + sr + 32) * a.lda + swc;
  const long boff0 = (long)(bn0 + sr) * a.ldb + swc;
  const long boff1 = (long)(bn0 + sr + 32) * a.ldb + swc;
  const u16 *a1p0 = A1b + aoff0, *a1p1 = A1b + aoff1;
  const u16 *a2p0 = A2b + aoff0, *a2p1 = A2b + aoff1;
  const u16 *b1p0 = B1b + boff0, *b1p1 = B1b + boff1;
  const u16 *b2p0 = B2b + boff0, *b2p1 = B2b + boff1;
  u16* lA10 = As1 + w * 512;  u16* lA11 = As1 + 2048 + w * 512;
  u16* lA20 = As2 + w * 512;  u16* lA21 = As2 + 2048 + w * 512;
  u16* lB10 = Bs1 + w * 512;  u16* lB11 = Bs1 + 2048 + w * 512;
  u16* lB20 = Bs2 + w * 512;  u16* lB21 = Bs2 + 2048 + w * 512;

  fv4 zero = {0.f, 0.f, 0.f, 0.f};
  fv4 p00 = zero, p01 = zero, p10 = zero, p11 = zero;
  fv4 q00 = zero, q01 = zero, q10 = zero, q11 = zero;
  const int r0 = lane & 15, kq8 = lane >> 4;
  const int nk = a.K >> 6;

  for (int kt = 0; kt < nk; ++kt) {
    __syncthreads();
    gll16(a1p0, lA10); gll16(a1p1, lA11);
    gll16(a2p0, lA20); gll16(a2p1, lA21);
    gll16(b1p0, lB10); gll16(b1p1, lB11);
    gll16(b2p0, lB20); gll16(b2p1, lB21);
    __syncthreads();
    a1p0 += 64; a1p1 += 64; a2p0 += 64; a2p1 += 64;
    b1p0 += 64; b1p1 += 64; b2p0 += 64; b2p1 += 64;
#pragma unroll
    for (int kc = 0; kc < 2; ++kc) {
      const int c8 = kq8 + 4 * kc;
      bh8 x0 = lds_rd(As1, wm + r0, c8);
      bh8 x1 = lds_rd(As1, wm + 16 + r0, c8);
      bh8 y0 = lds_rd(Bs1, wn + r0, c8);
      bh8 y1 = lds_rd(Bs1, wn + 16 + r0, c8);
      p00 = __builtin_amdgcn_mfma_f32_16x16x32_bf16(x0, y0, p00, 0, 0, 0);
      p01 = __builtin_amdgcn_mfma_f32_16x16x32_bf16(x0, y1, p01, 0, 0, 0);
      p10 = __builtin_amdgcn_mfma_f32_16x16x32_bf16(x1, y0, p10, 0, 0, 0);
      p11 = __builtin_amdgcn_mfma_f32_16x16x32_bf16(x1, y1, p11, 0, 0, 0);
      bh8 u0 = lds_rd(As2, wm + r0, c8);
      bh8 u1 = lds_rd(As2, wm + 16 + r0, c8);
      bh8 v0 = lds_rd(Bs2, wn + r0, c8);
      bh8 v1 = lds_rd(Bs2, wn + 16 + r0, c8);
      q00 = __builtin_amdgcn_mfma_f32_16x16x32_bf16(u0, v0, q00, 0, 0, 0);
      q01 = __builtin_amdgcn_mfma_f32_16x16x32_bf16(u0, v1, q01, 0, 0, 0);
      q10 = __builtin_amdgcn_mfma_f32_16x16x32_bf16(u1, v0, q10, 0, 0, 0);
      q11 = __builtin_amdgcn_mfma_f32_16x16x32_bf16(u1, v1, q11, 0, 0, 0);
    }
  }

  fv4 pa[2][2] = {{p00, p01}, {p10, p11}};
  fv4 qa[2][2] = {{q00, q01}, {q10, q11}};
#pragma unroll
  for (int rb = 0; rb < 2; ++rb) {
#pragma unroll
    for (int cbl = 0; cbl < 2; ++cbl) {
#pragma unroll
      for (int j = 0; j < 4; ++j) {
        const int r = bm0 + wm + rb * 16 + (lane >> 4) * 4 + j;
        const int c = bn0 + wn + cbl * 16 + (lane & 15);
        const float v1 = pa[rb][cbl][j];
        const float v2 = qa[rb][cbl][j];
        if (EPI == 2) {  // raw K1/K2
          const long idx = (long)z * a.sCz + (long)r * a.ldc + c;
          a.Cf[idx] = v1;
          a.Cf2[idx] = v2;
        } else {  // s: v1=T1, v2=T2
          const int lh = z * 256 + r;
          const int bl = z * 32 + (r >> 3);
          const float G2d = a.e1[c], B2d = a.e2[c];
          const float gv = a.e3[(long)bl * 512 + c];
          const float bev = a.e4[(long)bl * 512 + c];
          const float sv = v1 + B2d + G2d * (gv * v2 + bev * a.e5[lh] - a.e6[lh]);
          a.Cb[(long)z * a.sCz + (long)r * a.ldc + c] = f2b(sv);
        }
      }
    }
  }
}

// ===========================================================================
// Elementwise / transpose units
// ===========================================================================
__device__ __forceinline__ void tpf32_unit(const float* src, long lds, u16* dst, long ldd,
                                           int tr, int tc, int t, float T[64][65]) {
  const int c = t & 63, rg = t >> 6;
#pragma unroll 4
  for (int i = 0; i < 16; ++i) {
    const int r = rg + 4 * i;
    T[r][c] = src[(long)(tr * 64 + r) * lds + tc * 64 + c];
  }
  __syncthreads();
#pragma unroll 4
  for (int i = 0; i < 16; ++i) {
    const int r = rg + 4 * i;
    dst[(long)(tc * 64 + r) * ldd + tr * 64 + c] = f2b(T[c][r]);
  }
}

// Fused: kT transpose (bf16) + row-major k_bf emission. Same f2b of same f32
// values as the old cvt path -> bitwise-identical k_bf. Saves one full 8 MB
// re-read of k (the 1024-block cvt pass is deleted).
__device__ __forceinline__ void tpf32_kb_unit(const float* src, u16* dstT, u16* dstR,
                                              int tr, int tc, int t, float T[64][65]) {
  const int c = t & 63, rg = t >> 6;
#pragma unroll 4
  for (int i = 0; i < 16; ++i) {
    const int r = rg + 4 * i;
    const float v = src[(long)(tr * 64 + r) * 512 + tc * 64 + c];
    T[r][c] = v;
    dstR[(long)(tr * 64 + r) * 512 + tc * 64 + c] = f2b(v);
  }
  __syncthreads();
#pragma unroll 4
  for (int i = 0; i < 16; ++i) {
    const int r = rg + 4 * i;
    dstT[(long)(tc * 64 + r) * 256 + tr * 64 + c] = f2b(T[c][r]);
  }
}

__device__ __forceinline__ void tpb16_unit(const u16* src, u16* dst, int b, int w32,
                                           int t, float T[64][65]) {
  const int tr = w32 >> 3, tc = w32 & 7;
  const u16* s = src + (long)b * 131072;
  u16* d = dst + (long)b * 131072;
  const int c = t & 63, rg = t >> 6;
#pragma unroll 4
  for (int i = 0; i < 16; ++i) {
    const int r = rg + 4 * i;
    T[r][c] = b2f(s[(long)(tr * 64 + r) * 512 + tc * 64 + c]);
  }
  __syncthreads();
#pragma unroll 4
  for (int i = 0; i < 16; ++i) {
    const int r = rg + 4 * i;
    d[(long)(tc * 64 + r) * 256 + tr * 64 + c] = f2b(T[c][r]);
  }
}

__device__ __forceinline__ void cvt_unit(const float* s, u16* d, long blk, int t) {
  const long idx = blk * 2048 + t * 8;
  const float4 x0 = ld4(s + idx), x1 = ld4(s + idx + 4);
  const float v[8] = {x0.x, x0.y, x0.z, x0.w, x1.x, x1.y, x1.z, x1.w};
  *(uint4*)(d + idx) = pack8(v);
}

__device__ __forceinline__ void ln_unit(const FA& f, int u, int t) {
  const int lane = t & 63, e = lane * 8;
  const int row = u * 4 + (t >> 6);
  const float* p = f.condpre + (long)row * 512 + e;
  const float4 x0 = ld4(p), x1 = ld4(p + 4);
  float v[8] = {x0.x, x0.y, x0.z, x0.w, x1.x, x1.y, x1.z, x1.w};
  float s = 0.f, sq = 0.f;
#pragma unroll
  for (int i = 0; i < 8; ++i) { s += v[i]; sq += v[i] * v[i]; }
#pragma unroll
  for (int m = 1; m < 64; m <<= 1) { s += __shfl_xor(s, m); sq += __shfl_xor(sq, m); }
  const float mu = s * (1.f / 512.f);
  const float iv = rsqrtf(sq * (1.f / 512.f) - mu * mu + LN_EPS);
  const float4 g0 = ld4(f.ln1g + e), g1 = ld4(f.ln1g + e + 4);
  const float4 b0 = ld4(f.ln1b + e), b1 = ld4(f.ln1b + e + 4);
  const float gg[8] = {g0.x, g0.y, g0.z, g0.w, g1.x, g1.y, g1.z, g1.w};
  const float bb[8] = {b0.x, b0.y, b0.z, b0.w, b1.x, b1.y, b1.z, b1.w};
  float o[8], osq[8];
#pragma unroll
  for (int i = 0; i < 8; ++i) {
    o[i] = (v[i] - mu) * iv * gg[i] + bb[i];
    osq[i] = o[i] * o[i];
  }
  *(uint4*)(f.cb_bf + (long)row * 512 + e) = pack8(o);
  *(uint4*)(f.cbsq_bf + (long)row * 512 + e) = pack8(osq);
}

__device__ __forceinline__ void a96_unit(const FA& f, int u, int t) {
  const int lane = t & 63, e = lane * 8;
  const int bl = u * 4 + (t >> 6);
  const int b = bl >> 5, l = bl & 31;
  const float4 ga0 = ld4(f.gam + (long)bl * 512 + e), ga1 = ld4(f.gam + (long)bl * 512 + e + 4);
  const float4 be0 = ld4(f.bet + (long)bl * 512 + e), be1 = ld4(f.bet + (long)bl * 512 + e + 4);
  const float gv[8] = {ga0.x, ga0.y, ga0.z, ga0.w, ga1.x, ga1.y, ga1.z, ga1.w};
  const float bv[8] = {be0.x, be0.y, be0.z, be0.w, be1.x, be1.y, be1.z, be1.w};
  float gg[8], gb[8]; float s1 = 0.f, s2 = 0.f;
#pragma unroll
  for (int i = 0; i < 8; ++i) {
    gg[i] = gv[i] * gv[i]; gb[i] = gv[i] * bv[i];
    s1 += bv[i]; s2 += bv[i] * bv[i];
  }
  const long basei = ((long)b * 96 + l) * 512 + e;
  *(uint4*)(f.A96_bf + basei) = pack8(gv);
  *(uint4*)(f.A96_bf + basei + 32 * 512) = pack8(gb);
  *(uint4*)(f.A96_bf + basei + 64 * 512) = pack8(gg);
#pragma unroll
  for (int m = 1; m < 64; m <<= 1) { s1 += __shfl_xor(s1, m); s2 += __shfl_xor(s2, m); }
  if (lane == 0) { f.sum_be[bl] = s1; f.sum_be2[bl] = s2; }
}

__device__ __forceinline__ void csum_unit(const FA& f, int u, int t) {
  const int lane = t & 63, e = lane * 8;
  const int lh = u * 4 + (t >> 6);
  const int bl = lh >> 3;
  const uint4 up = *(const uint4*)(f.u_bf + (long)lh * 512 + e);
  const u16* us = (const u16*)&up;
  const float4 be0 = ld4(f.bet + (long)bl * 512 + e), be1 = ld4(f.bet + (long)bl * 512 + e + 4);
  const float4 G0 = ld4(f.ln2g + e), G1 = ld4(f.ln2g + e + 4);
  const float4 B0 = ld4(f.ln2b + e), B1 = ld4(f.ln2b + e + 4);
  const float bv[8] = {be0.x, be0.y, be0.z, be0.w, be1.x, be1.y, be1.z, be1.w};
  const float Gv[8] = {G0.x, G0.y, G0.z, G0.w, G1.x, G1.y, G1.z, G1.w};
  const float Bv[8] = {B0.x, B0.y, B0.z, B0.w, B1.x, B1.y, B1.z, B1.w};
  float a2 = 0.f, a3 = 0.f, a4 = 0.f;
#pragma unroll
  for (int i = 0; i < 8; ++i) {
    const float uu = b2f(us[i]);
    const float t1 = Gv[i] * uu;
    a2 += bv[i] * t1; a3 += t1; a4 += Bv[i] * uu;
  }
#pragma unroll
  for (int m = 1; m < 64; m <<= 1) {
    a2 += __shfl_xor(a2, m); a3 += __shfl_xor(a3, m); a4 += __shfl_xor(a4, m);
  }
  if (lane == 0) { f.c2[lh] = a2; f.c3[lh] = a3; f.c4[lh] = a4; }
}

// softmax + logits assembly (reads raw K1/K2)
__device__ __forceinline__ void softmax2_unit(const FA& f, int u, int t) {
  const int lane = t & 63, e = lane * 4;
  const int lh = u * 4 + (t >> 6);
  const int b = lh >> 8, l = (lh >> 3) & 31, bl = lh >> 3;
  const float4 k1 = ld4(f.K1 + (long)lh * 256 + e);
  const float4 k2 = ld4(f.K2 + (long)lh * 256 + e);
  const float* Pb = f.P + ((long)b * 96 + l) * 256 + e;
  const float4 p0 = ld4(Pb), pgb = ld4(Pb + 32 * 256), pg2 = ld4(Pb + 64 * 256);
  const float sbe = f.sum_be[bl], sbe2 = f.sum_be2[bl];
  const float C2 = f.c2[lh], C3 = f.c3[lh], C4 = f.c4[lh];
  const float k1s[4] = {k1.x, k1.y, k1.z, k1.w};
  const float k2s[4] = {k2.x, k2.y, k2.z, k2.w};
  const float p0s[4] = {p0.x, p0.y, p0.z, p0.w};
  const float pgbs[4] = {pgb.x, pgb.y, pgb.z, pgb.w};
  const float pg2s[4] = {pg2.x, pg2.y, pg2.z, pg2.w};
  float mu[4], iv[4], lgs[4];
#pragma unroll
  for (int i = 0; i < 4; ++i) {
    mu[i] = (p0s[i] + sbe) * (1.f / 512.f);
    const float msq = (pg2s[i] + 2.f * pgbs[i] + sbe2) * (1.f / 512.f);
    iv[i] = rsqrtf(msq - mu[i] * mu[i] + LN_EPS);
    lgs[i] = k1s[i] + C4 + iv[i] * (k2s[i] + C2 - mu[i] * C3);
  }
  float mx = fmaxf(fmaxf(lgs[0], lgs[1]), fmaxf(lgs[2], lgs[3]));
#pragma unroll
  for (int m = 1; m < 64; m <<= 1) mx = fmaxf(mx, __shfl_xor(mx, m));
  float ex[4]; float z = 0.f;
#pragma unroll
  for (int i = 0; i < 4; ++i) { ex[i] = expf(lgs[i] - mx); z += ex[i]; }
#pragma unroll
  for (int m = 1; m < 64; m <<= 1) z += __shfl_xor(z, m);
  const float rz = 1.f / z;
  float wv[4], w1v[4]; float s1 = 0.f, s2 = 0.f;
#pragma unroll
  for (int i = 0; i < 4; ++i) {
    wv[i] = ex[i] * rz;
    w1v[i] = wv[i] * iv[i];
    s1 += w1v[i]; s2 += w1v[i] * mu[i];
  }
  uint2 wp, w1p;
  wp.x = pk2(wv[0], wv[1]); wp.y = pk2(wv[2], wv[3]);
  w1p.x = pk2(w1v[0], w1v[1]); w1p.y = pk2(w1v[2], w1v[3]);
  *(uint2*)(f.w_bf + (long)lh * 256 + e) = wp;
  *(uint2*)(f.W1_bf + (long)lh * 256 + e) = w1p;
#pragma unroll
  for (int m = 1; m < 64; m <<= 1) { s1 += __shfl_xor(s1, m); s2 += __shfl_xor(s2, m); }
  if (lane == 0) { f.S1[lh] = s1; f.S2[lh] = s2; }
}

// ===========================================================================
// Phase kernels (7 dispatches, round-7 DAG)
// ===========================================================================
// A: G2-f32(512) + G1a-f32(128) + G1b-f32(64) + Wv cvt(128) + Wfc cvt(128)
//    + WkT(64) + kT+k_bf fused(512) = 1536
__global__ __launch_bounds__(256) void pA_k(FA f) {
  __shared__ __align__(16) char smem[16704];
  u16* As = (u16*)smem;
  u16* Bs = (u16*)(smem + 8192);
  float (*T)[65] = (float(*)[65])smem;
  const int u = blockIdx.x, t = threadIdx.x;
  if (u < 512) {
    GAF a = {}; a.Af = f.k; a.Bf = f.Wvp; a.lda = 512; a.ldb = 512;
    a.Cf = f.condpre; a.ldc = 512; a.M = 4096; a.K = 512; a.epi = 4; a.e0 = f.bvp;
    gemm_core_f32(a, As, Bs, u % 64, u / 64, t);
  } else if (u < 640) {
    const int r = u - 512;
    GAF a = {}; a.Af = f.q; a.Bf = f.Wg; a.lda = 512; a.ldb = 512;
    a.Cf = f.gam; a.Cf2 = f.bet; a.ldc = 512; a.M = 512; a.K = 512; a.epi = 2; a.e0 = f.bg;
    gemm_core_f32(a, As, Bs, r % 8, r / 8, t);
  } else if (u < 704) {
    const int r = u - 640;
    GAF a = {}; a.Af = f.q; a.Bf = f.Wq; a.lda = 512; a.ldb = 512;
    a.Cb = f.qh_bf; a.ldc = 512; a.M = 512; a.K = 512; a.epi = 1;
    gemm_core_f32(a, As, Bs, r % 8, r / 8, t);
  } else if (u < 832) {
    cvt_unit(f.Wv, f.Wv_bf, u - 704, t);
  } else if (u < 960) {
    cvt_unit(f.Wfc, f.Wfc_bf, u - 832, t);
  } else if (u < 1024) {
    const int tt = u - 960;
    tpf32_unit(f.Wk, 512, f.WkT_bf, 512, tt >> 3, tt & 7, t, T);
  } else {
    const int tt = u - 1024;
    const int b = tt >> 5, w32 = tt & 31;
    tpf32_kb_unit(f.k + (long)b * 131072, f.kT_bf + (long)b * 131072,
                  f.k_bf + (long)b * 131072, w32 >> 3, w32 & 7, t, T);
  }
}

// B: LN(1024) + A96(128) + Gu·w1(512) = 1664
__global__ __launch_bounds__(256) void pB_k(FA f) {
  __shared__ __align__(16) char smem[16384];
  u16* As = (u16*)smem;
  u16* Bs = (u16*)(smem + 8192);
  const int u = blockIdx.x, t = threadIdx.x;
  if (u < 1024) {
    ln_unit(f, u, t);
  } else if (u < 1152) {
    a96_unit(f, u - 1024, t);
  } else {
    const int r = u - 1152;
    GA a = {}; a.A = f.qh_bf; a.lda = 512; a.sAz = 64;
    a.B = f.WkT_bf; a.ldb = 512; a.sBz = 64;
    a.Cb = f.u_bf; a.Cb2 = f.w1_bf; a.ldc = 512; a.M = 512; a.K = 64; a.epi = 6;
    a.e0 = f.gam; a.e1 = f.ln2g;
    gemm_core(a, As, Bs, r % 8, (r / 8) % 8, r / 64, t);
  }
}

// C: GP(128) + cbT(512) + csum(1024) + GK-raw(256) = 1920
__global__ __launch_bounds__(256) void pC_k(FA f) {
  __shared__ __align__(16) char smem[32768];
  const int u = blockIdx.x, t = threadIdx.x;
  if (u < 128) {
    u16* As = (u16*)smem; u16* Bs = (u16*)(smem + 8192);
    GA a = {}; a.A = f.A96_bf; a.lda = 512; a.sAz = 96 * 512;
    a.B = f.cb_bf; a.Balt = f.cbsq_bf; a.ldb = 512; a.sBz = 256 * 512;
    a.Cf = f.P; a.ldc = 256; a.sCz = 96 * 256; a.M = 96; a.K = 512; a.epi = 0;
    gemm_core(a, As, Bs, u % 2, (u / 2) % 4, u / 8, t);
  } else if (u < 640) {
    float (*T)[65] = (float(*)[65])smem;
    const int tt = u - 128;
    tpb16_unit(f.cb_bf, f.cbT_bf, tt >> 5, tt & 31, t, T);
  } else if (u < 1664) {
    csum_unit(f, u - 640, t);
  } else {
    const int r = u - 1664;
    u16* As1 = (u16*)smem; u16* As2 = (u16*)(smem + 8192);
    u16* Bs1 = (u16*)(smem + 16384); u16* Bs2 = (u16*)(smem + 24576);
    GA2 d = {};
    d.A1 = f.u_bf; d.A2 = f.w1_bf; d.B1 = f.k_bf; d.B2 = f.cb_bf;
    d.lda = 512; d.ldb = 512; d.sAz = 256 * 512; d.sBz = 256 * 512;
    d.Cf = f.K1; d.Cf2 = f.K2; d.ldc = 256; d.sCz = 256 * 256; d.M = 256; d.K = 512;
    gemm2_core(d, As1, As2, Bs1, Bs2, r % 4, (r / 4) % 4, r / 16, t, 2);
  }
}

// D: softmax + logits assembly (1024)
__global__ __launch_bounds__(256) void pD_k(FA f) {
  softmax2_unit(f, blockIdx.x, threadIdx.x);
}

// E: GT (512)
__global__ __launch_bounds__(256) void pE_k(FA f) {
  __shared__ __align__(16) char smem[32768];
  u16* As1 = (u16*)smem; u16* As2 = (u16*)(smem + 8192);
  u16* Bs1 = (u16*)(smem + 16384); u16* Bs2 = (u16*)(smem + 24576);
  const int u = blockIdx.x, t = threadIdx.x;
  GA2 d = {};
  d.A1 = f.w_bf; d.A2 = f.W1_bf; d.B1 = f.kT_bf; d.B2 = f.cbT_bf;
  d.lda = 256; d.ldb = 256; d.sAz = 256 * 256; d.sBz = 512 * 256;
  d.Cb = f.s_bf; d.ldc = 512; d.sCz = 256 * 512; d.M = 256; d.K = 256;
  d.e1 = f.ln2g; d.e2 = f.ln2b; d.e3 = f.gam; d.e4 = f.bet; d.e5 = f.S1; d.e6 = f.S2;
  gemm2_core(d, As1, As2, Bs1, Bs2, u % 4, (u / 4) % 8, u / 32, t, 1);
}

// F: attn = s_h @ Wv_h^T (64)
__global__ __launch_bounds__(256) void pF_k(FA f) {
  __shared__ __align__(16) char smem[16384];
  u16* As = (u16*)smem; u16* Bs = (u16*)(smem + 8192);
  const int u = blockIdx.x, t = threadIdx.x;
  GA a = {}; a.A = f.s_bf; a.lda = 4096; a.sAz = 512;
  a.B = f.Wv_bf; a.ldb = 512; a.sBz = 64 * 512;
  a.Cb = f.attn_bf; a.ldc = 512; a.sCz = 64; a.M = 512; a.K = 512; a.epi = 1;
  gemm_core(a, As, Bs, u % 8, 0, u / 8, t);
}

// G: out = attn @ Wfc^T (64)
__global__ __launch_bounds__(256) void pG_k(FA f) {
  __shared__ __align__(16) char smem[16384];
  u16* As = (u16*)smem; u16* Bs = (u16*)(smem + 8192);
  const int u = blockIdx.x, t = threadIdx.x;
  GA a = {}; a.A = f.attn_bf; a.lda = 512;
  a.B = f.Wfc_bf; a.ldb = 512;
  a.Cf = f.out; a.ldc = 512; a.M = 512; a.K = 512; a.epi = 0;
  gemm_core(a, As, Bs, u % 8, u / 8, 0, t);
}

}  // namespace

extern "C" void kernel_launch(void* const* d_in, const int* in_sizes, int n_in,
                              void* d_out, int out_size, void* d_ws, size_t ws_size,
                              hipStream_t stream) {
  (void)in_sizes; (void)n_in; (void)out_size;
  FA fa;
  fa.q    = (const float*)d_in[0];
  fa.k    = (const float*)d_in[1];
  fa.Wq   = (const float*)d_in[3];
  fa.Wk   = (const float*)d_in[4];
  fa.Wv   = (const float*)d_in[5];
  fa.Wfc  = (const float*)d_in[6];
  fa.Wg   = (const float*)d_in[7];
  fa.bg   = (const float*)d_in[8];
  fa.Wvp  = (const float*)d_in[9];
  fa.bvp  = (const float*)d_in[10];
  fa.ln1g = (const float*)d_in[11];
  fa.ln1b = (const float*)d_in[12];
  fa.ln2g = (const float*)d_in[13];
  fa.ln2b = (const float*)d_in[14];
  fa.out  = (float*)d_out;

  char* base = (char*)d_ws;
  size_t off = 0;
  auto au16 = [&](size_t n) -> u16* {
    u16* p = (u16*)(base + off); off = (off + n * 2 + 255) & ~(size_t)255; return p;
  };
  auto af32 = [&](size_t n) -> float* {
    float* p = (float*)(base + off); off = (off + n * 4 + 255) & ~(size_t)255; return p;
  };
  (void)au16(262144);               // layout parity (unused)
  (void)au16(524288);
  (void)au16(262144);
  (void)au16(262144);
  fa.WkT_bf  = au16(262144);
  fa.Wv_bf   = au16(262144);
  fa.Wfc_bf  = au16(262144);
  fa.k_bf    = au16(2097152);
  fa.kT_bf   = au16(2097152);
  fa.qh_bf   = au16(262144);
  fa.gam     = af32(262144);
  fa.bet     = af32(262144);
  fa.condpre = af32(2097152);       // K1 = first half, K2 = second half (post-LN)
  fa.cb_bf   = au16(2097152);
  fa.cbT_bf  = au16(2097152);
  fa.u_bf    = au16(2097152);
  fa.w1_bf   = au16(2097152);
  fa.c2      = af32(4096);
  fa.c3      = af32(4096);
  fa.c4      = af32(4096);
  fa.A96_bf  = au16(16 * 96 * 512);
  fa.sum_be  = af32(512);
  fa.sum_be2 = af32(512);
  fa.P       = af32(16 * 96 * 256);
  float* sbuf   = af32(1048576);
  float* logits = af32(1048576);    // holds cb^2 (bf16) from LN
  fa.w_bf    = au16(1048576);
  fa.W1_bf   = au16(1048576);
  fa.S1      = af32(4096);
  fa.S2      = af32(4096);
  fa.attn_bf = au16(262144);
  const size_t need = off;
  fa.s_bf    = (u16*)sbuf;
  fa.cbsq_bf = (u16*)logits;
  fa.K1      = fa.condpre;          // condpre dead after LN (phase B)
  fa.K2      = fa.condpre + 1048576;

  if (ws_size < need) return;

  const dim3 blk(256);
  pA_k<<<dim3(1536), blk, 0, stream>>>(fa);
  pB_k<<<dim3(1664), blk, 0, stream>>>(fa);
  pC_k<<<dim3(1920), blk, 0, stream>>>(fa);
  pD_k<<<dim3(1024), blk, 0, stream>>>(fa);
  pE_k<<<dim3(512),  blk, 0, stream>>>(fa);
  pF_k<<<dim3(64),   blk, 0, stream>>>(fa);
  pG_k<<<dim3(64),   blk, 0, stream>>>(fa);
}